// Round 8
// baseline (484.273 us; speedup 1.0000x reference)
//
#include <hip/hip_runtime.h>
#include <math.h>
#include <float.h>

#define BATCH 4
#define CH    256
#define NT    4096
#define NCTX  8192
#define KI    8

// coarse-selection geometry
#define CSEL    10                 // per-split top-C after lane-half merge (>=8 => safe)
#define DNSPLIT 8                  // ctx splits (grid fill)
#define CTX_PER (NCTX / DNSPLIT)   // 1024
#define NTILE   (CTX_PER / 32)     // 32 tiles of 32 ctx
#define NKEY    (DNSPLIT * CSEL)   // 80 packed keys per target
#define RESC    12                 // keys kept for exact fp64 rescore

typedef __attribute__((ext_vector_type(8)))  __bf16 bf16x8;
typedef __attribute__((ext_vector_type(16))) float  f32x16;

__device__ __forceinline__ unsigned short bf16_rne(float v) {
  unsigned u = __float_as_uint(v);
  return (unsigned short)((u + 0x7fffu + ((u >> 16) & 1u)) >> 16);
}

// ---------------- merged transpose: [CH][NT] -> [NT][CH] fp32 + bf16 hi/lo, + ctx norms ----------------
__global__ __launch_bounds__(256) void k_transpose2(const float* __restrict__ Xt,
                                                    const float* __restrict__ Xc1,
                                                    const float* __restrict__ Xc2,
                                                    float* __restrict__ Q,
                                                    float* __restrict__ P,
                                                    unsigned short* __restrict__ XtBh,
                                                    unsigned short* __restrict__ XtBl,
                                                    unsigned short* __restrict__ XcBh,
                                                    unsigned short* __restrict__ XcBl,
                                                    float* __restrict__ nrm) {
  __shared__ float tile[64][33];
  __shared__ float ps[8][32];
  const int which = blockIdx.z >> 2, b = blockIdx.z & 3;
  const float* src;
  float* dF; unsigned short *dH, *dL; float* nrmp = nullptr;
  if (which == 0) {
    src = Xt + (long)b * CH * NT;
    dF = Q + (long)b * NT * CH;
    dH = XtBh + (long)b * NT * CH;  dL = XtBl + (long)b * NT * CH;
  } else if (which == 1) {
    src = Xc1 + (long)b * CH * NT;
    dF = P + (long)b * NCTX * CH;
    dH = XcBh + (long)b * NCTX * CH;  dL = XcBl + (long)b * NCTX * CH;
    nrmp = nrm + (long)b * NCTX;
  } else {
    src = Xc2 + (long)b * CH * NT;
    dF = P + ((long)b * NCTX + NT) * CH;
    dH = XcBh + ((long)b * NCTX + NT) * CH;  dL = XcBl + ((long)b * NCTX + NT) * CH;
    nrmp = nrm + (long)b * NCTX + NT;
  }
  const int m0 = blockIdx.x * 32, c0 = blockIdx.y * 64;
  const int tx = threadIdx.x, ty = threadIdx.y;
  float part = 0.f;
#pragma unroll
  for (int i = ty; i < 64; i += 8) {
    float v = src[(long)(c0 + i) * NT + (m0 + tx)];
    tile[i][tx] = v;
    part = fmaf(v, v, part);
  }
  if (which) ps[ty][tx] = part;
  __syncthreads();
#pragma unroll
  for (int i = ty; i < 32; i += 8) {
    float v0 = tile[2 * tx][i];
    float v1 = tile[2 * tx + 1][i];
    long o = (long)(m0 + i) * CH + (c0 + 2 * tx);
    float2 f2; f2.x = v0; f2.y = v1;
    *(float2*)&dF[o] = f2;
    unsigned short h0 = bf16_rne(v0), h1 = bf16_rne(v1);
    ushort2 h2; h2.x = h0; h2.y = h1;
    *(ushort2*)&dH[o] = h2;
    float hf0 = __uint_as_float((unsigned)h0 << 16);
    float hf1 = __uint_as_float((unsigned)h1 << 16);
    ushort2 l2; l2.x = bf16_rne(v0 - hf0); l2.y = bf16_rne(v1 - hf1);
    *(ushort2*)&dL[o] = l2;
  }
  if (which && ty == 0) {
    float s = 0.f;
#pragma unroll
    for (int j = 0; j < 8; ++j) s += ps[j][tx];
    atomicAdd(&nrmp[m0 + tx], -0.5f * s);
  }
}

// ---------------- W transpose: fp32 [CH(k)][CH(n)] -> bf16 hi/lo WT[n][k]; z = which W ----------------
__global__ __launch_bounds__(256) void k_wtrans(const float* __restrict__ W1,
                                                const float* __restrict__ W2,
                                                unsigned short* __restrict__ WT1h,
                                                unsigned short* __restrict__ WT1l,
                                                unsigned short* __restrict__ WT2h,
                                                unsigned short* __restrict__ WT2l) {
  __shared__ float tile[32][33];
  const float* W = blockIdx.z ? W2 : W1;
  unsigned short* WTh = blockIdx.z ? WT2h : WT1h;
  unsigned short* WTl = blockIdx.z ? WT2l : WT1l;
  const int n0 = blockIdx.x * 32, k0 = blockIdx.y * 32;
  const int tx = threadIdx.x, ty = threadIdx.y;
#pragma unroll
  for (int i = ty; i < 32; i += 8)
    tile[i][tx] = W[(k0 + i) * CH + (n0 + tx)];
  __syncthreads();
#pragma unroll
  for (int i = ty; i < 32; i += 8) {
    float v = tile[tx][i];
    int o = (n0 + i) * CH + (k0 + tx);
    unsigned short h = bf16_rne(v);
    WTh[o] = h;
    float hf = __uint_as_float((unsigned)h << 16);
    WTl[o] = bf16_rne(v - hf);
  }
}

// ---------------- MFMA coarse scorer + per-lane top-CSEL, XCD-swizzled 1D grid ----------------
// lid = (b*2+jh) + 8*(jw + 16*split): XCD(lid)=lid%8 => each XCD owns one (batch, j-half),
// split varies slowest -> per-XCD L2 set = 0.5MB ctx slice (x16 reuse) + 1MB targets (x8 reuse).
// Wave-uniform skip guard on the bubble insert (insert is idempotent for non-qualifying keys).
__global__ __launch_bounds__(256) void k_dist_mfma(const __bf16* __restrict__ XcB,
                                                   const __bf16* __restrict__ XtB,
                                                   const float* __restrict__ nrm,
                                                   unsigned* __restrict__ cand) {
  __shared__ __bf16 lds[2][32 * CH];   // 2 x 16 KB ctx tiles, fragment-linear order
  const int lid = blockIdx.x;
  const int xk = lid & 7, rest = lid >> 3;
  const int b = xk >> 1, jh = xk & 1;
  const int jw = rest & 15, split = rest >> 4;
  const int t = threadIdx.x, w = t >> 6, lane = t & 63;
  const int l31 = lane & 31, lh = lane >> 5;
  const int tgt0 = (jh * 16 + jw) * 128 + w * 32;
  const int cbase = split * CTX_PER;
  const float* nrmt = nrm + (long)b * NCTX + cbase;   // -0.5*|c|^2

  const __bf16* tp = XtB + ((long)b * NT + tgt0 + l31) * CH + lh * 8;
  bf16x8 bfrag[16];
#pragma unroll
  for (int s = 0; s < 16; ++s) bfrag[s] = *(const bf16x8*)(tp + s * 16);

  unsigned kd[CSEL];
#pragma unroll
  for (int q = 0; q < CSEL; ++q) kd[q] = 0xFFFFFFFFu;

  const __bf16* cp = XcB + ((long)b * NCTX + cbase + l31) * CH;

  auto STAGE = [&](int buf, int jt) {
#pragma unroll
    for (int r = 0; r < 4; ++r) {
      int c = r * 4 + w;
      const __bf16* src = cp + (long)jt * 32 * CH + (c * 2 + lh) * 8;
      __bf16* dst = &lds[buf][c * 512];
      __builtin_amdgcn_global_load_lds((const __attribute__((address_space(1))) void*)src,
                                       (__attribute__((address_space(3))) void*)dst,
                                       16, 0, 0);
    }
  };

  STAGE(0, 0);
  __syncthreads();

  int cur = 0;
  for (int jt = 0; jt < NTILE; ++jt) {
    if (jt + 1 < NTILE) STAGE(cur ^ 1, jt + 1);

    const int ct0 = jt * 32;
    f32x16 acc;
#pragma unroll
    for (int g = 0; g < 4; ++g) {
      float4 nv = *(const float4*)&nrmt[ct0 + 8 * g + 4 * lh];
      acc[4 * g + 0] = nv.x; acc[4 * g + 1] = nv.y;
      acc[4 * g + 2] = nv.z; acc[4 * g + 3] = nv.w;
    }
#pragma unroll
    for (int s = 0; s < 16; ++s) {
      bf16x8 a = *(const bf16x8*)(&lds[cur][s * 512 + lane * 8]);
      acc = __builtin_amdgcn_mfma_f32_32x32x16_bf16(a, bfrag[s], acc, 0, 0, 0);
    }

#pragma unroll
    for (int reg = 0; reg < 16; ++reg) {
      const int row = (reg & 3) + 8 * (reg >> 2) + lh * 4;
      float sc = fmaf(acc[reg], -2.0f, 512.0f);
      unsigned key = (__float_as_uint(sc) & 0xFFFFF800u) | (unsigned)ct0 | (unsigned)row;
      if (__any(key < kd[CSEL - 1])) {   // wave-uniform skip; bubble is idempotent
#pragma unroll
        for (int q = 0; q < CSEL; ++q) {
          unsigned lo = min(key, kd[q]);
          key = max(key, kd[q]);
          kd[q] = lo;
        }
      }
    }
    __syncthreads();
    cur ^= 1;
  }

  unsigned oth[CSEL];
#pragma unroll
  for (int q = 0; q < CSEL; ++q) oth[q] = (unsigned)__shfl_xor((int)kd[q], 32, 64);
  if (lh == 0) {
    long ob = (((long)b * NT + tgt0 + l31) * DNSPLIT + split) * CSEL;
#pragma unroll
    for (int q = 0; q < CSEL; ++q)
      cand[ob + q] = min(kd[q], oth[CSEL - 1 - q]);
  }
}

// ---------------- rescore: coarse top-RESC of 80 keys, fp64 exact, rank-8 + counts ----------------
__global__ __launch_bounds__(64) void k_rescore(const float* __restrict__ XtT,
                                                const float* __restrict__ XcT,
                                                const unsigned* __restrict__ cand,
                                                int* __restrict__ knn,
                                                unsigned* __restrict__ counts) {
  const int n = blockIdx.x, b = blockIdx.y, lane = threadIdx.x;
  const int grp = lane >> 4, gl = lane & 15;
  __shared__ unsigned sk[NKEY];
  __shared__ int cidx[RESC];
  __shared__ double sd[RESC];
  __shared__ int sj[RESC];
  const unsigned* kp = cand + ((long)b * NT + n) * NKEY;
  unsigned k0 = kp[lane];
  unsigned k1 = (lane < NKEY - 64) ? kp[64 + lane] : 0xFFFFFFFFu;
  sk[lane] = k0;
  if (lane < NKEY - 64) sk[64 + lane] = k1;
  __syncthreads();
  int r0 = 0, r1 = 0;
  for (int i = 0; i < NKEY; ++i) {
    unsigned s = sk[i];
    r0 += (s < k0 || (s == k0 && i < lane)) ? 1 : 0;
    r1 += (s < k1 || (s == k1 && i < 64 + lane)) ? 1 : 0;
  }
  if (r0 < RESC) cidx[r0] = (lane / CSEL) * CTX_PER + (int)(k0 & 0x7FFu);
  if (lane < NKEY - 64 && r1 < RESC)
    cidx[r1] = ((64 + lane) / CSEL) * CTX_PER + (int)(k1 & 0x7FFu);
  __syncthreads();

  const float* xt = XtT + ((long)b * NT + n) * CH + gl * 16;
  double xa[16];
#pragma unroll
  for (int r = 0; r < 4; ++r) {
    float4 v = *(const float4*)(xt + r * 4);
    xa[4 * r + 0] = (double)v.x; xa[4 * r + 1] = (double)v.y;
    xa[4 * r + 2] = (double)v.z; xa[4 * r + 3] = (double)v.w;
  }
#pragma unroll
  for (int q0 = 0; q0 < RESC; q0 += 4) {
    int q = q0 + grp;
    int j = cidx[q];
    const float* xc = XcT + ((long)b * NCTX + j) * CH + gl * 16;
    double acc = 0.0;
#pragma unroll
    for (int r = 0; r < 4; ++r) {
      float4 v = *(const float4*)(xc + r * 4);
      double d0 = xa[4 * r + 0] - (double)v.x; acc = fma(d0, d0, acc);
      double d1 = xa[4 * r + 1] - (double)v.y; acc = fma(d1, d1, acc);
      double d2 = xa[4 * r + 2] - (double)v.z; acc = fma(d2, d2, acc);
      double d3 = xa[4 * r + 3] - (double)v.w; acc = fma(d3, d3, acc);
    }
#pragma unroll
    for (int off = 8; off > 0; off >>= 1) acc += __shfl_xor(acc, off, 64);
    if (gl == 0) { sd[q] = acc; sj[q] = j; }
  }
  __syncthreads();
  double dq = (lane < RESC) ? sd[lane] : DBL_MAX;
  int    jq = (lane < RESC) ? sj[lane] : 0x7fffffff;
  int rank = 0;
#pragma unroll
  for (int i = 0; i < RESC; ++i) {
    double di = sd[i]; int ji = sj[i];
    rank += (di < dq || (di == dq && ji < jq)) ? 1 : 0;
  }
  if (lane < RESC && rank < KI) {
    knn[((long)b * NT + n) * KI + rank] = jq;
    atomicAdd(&counts[(long)b * NCTX + jq], 1u);
  }
}

// ---------------- bf16 MFMA GEMM + bias, 3-term hi/lo split (node2edge linear) ----------------
__global__ __launch_bounds__(256) void k_gemm_mfma(const unsigned short* __restrict__ Ah,
                                                   const unsigned short* __restrict__ Al,
                                                   const unsigned short* __restrict__ WTh,
                                                   const unsigned short* __restrict__ WTl,
                                                   const float* __restrict__ bias,
                                                   float* __restrict__ out, int M) {
  __shared__ __bf16 ldsH[32 * CH];
  __shared__ __bf16 ldsL[32 * CH];
  const int b = blockIdx.y;
  const int m0 = blockIdx.x * 32;
  const int t = threadIdx.x, w = t >> 6, lane = t & 63;
  const int l31 = lane & 31, lh = lane >> 5;
  const long abase = (long)b * M * CH;
  const unsigned short* pH = Ah + abase + (long)(m0 + l31) * CH;
  const unsigned short* pL = Al + abase + (long)(m0 + l31) * CH;
#pragma unroll
  for (int r = 0; r < 4; ++r) {
    int c = r * 4 + w;
    __builtin_amdgcn_global_load_lds(
        (const __attribute__((address_space(1))) void*)(pH + (c * 2 + lh) * 8),
        (__attribute__((address_space(3))) void*)&ldsH[c * 512], 16, 0, 0);
    __builtin_amdgcn_global_load_lds(
        (const __attribute__((address_space(1))) void*)(pL + (c * 2 + lh) * 8),
        (__attribute__((address_space(3))) void*)&ldsL[c * 512], 16, 0, 0);
  }
  __syncthreads();

  const int n0 = w * 64;
  f32x16 acc0, acc1;
#pragma unroll
  for (int i = 0; i < 16; ++i) { acc0[i] = 0.f; acc1[i] = 0.f; }
#pragma unroll
  for (int s = 0; s < 16; ++s) {
    bf16x8 ah = *(const bf16x8*)&ldsH[s * 512 + lane * 8];
    bf16x8 al = *(const bf16x8*)&ldsL[s * 512 + lane * 8];
    const int koff = lh * 8 + s * 16;
    bf16x8 bh0 = *(const bf16x8*)&WTh[(n0 + l31) * CH + koff];
    bf16x8 bl0 = *(const bf16x8*)&WTl[(n0 + l31) * CH + koff];
    bf16x8 bh1 = *(const bf16x8*)&WTh[(n0 + 32 + l31) * CH + koff];
    bf16x8 bl1 = *(const bf16x8*)&WTl[(n0 + 32 + l31) * CH + koff];
    acc0 = __builtin_amdgcn_mfma_f32_32x32x16_bf16(ah, bh0, acc0, 0, 0, 0);
    acc1 = __builtin_amdgcn_mfma_f32_32x32x16_bf16(ah, bh1, acc1, 0, 0, 0);
    acc0 = __builtin_amdgcn_mfma_f32_32x32x16_bf16(ah, bl0, acc0, 0, 0, 0);
    acc1 = __builtin_amdgcn_mfma_f32_32x32x16_bf16(ah, bl1, acc1, 0, 0, 0);
    acc0 = __builtin_amdgcn_mfma_f32_32x32x16_bf16(al, bh0, acc0, 0, 0, 0);
    acc1 = __builtin_amdgcn_mfma_f32_32x32x16_bf16(al, bh1, acc1, 0, 0, 0);
  }
  float* ob = out + abase;
  float bi0 = bias[n0 + l31], bi1 = bias[n0 + 32 + l31];
#pragma unroll
  for (int reg = 0; reg < 16; ++reg) {
    int row = (reg & 3) + 8 * (reg >> 2) + 4 * lh;
    ob[(long)(m0 + row) * CH + n0 + l31]      = acc0[reg] + bi0;
    ob[(long)(m0 + row) * CH + n0 + 32 + l31] = acc1[reg] + bi1;
  }
}

// ---------------- fused gather + edge2node GEMM + dual output (out_t direct, R rows for scatter) ----------------
// Phase 1: X_edge = (Xn_t[n] + sum Xn_c[knn])/9 -> bf16 hi/lo in LDS (fragment-linear).
// Phase 2: C[ch_out][node] = (W2h+W2l)^T x (XeH+XeL), 3-term MFMA (a=WT2 rows, b=Xe).
// Phase 3: +bias; store out_t[ch][node] coalesced; LDS-pad transpose -> R[node][ch] for scatter.
// In-place: reads Xn_t rows from R (phase 1), writes X_et rows to R (phase 3) - block-private rows.
__global__ __launch_bounds__(256) void k_gg2(const float* __restrict__ Xn_c,
                                             const int* __restrict__ knn,
                                             const unsigned short* __restrict__ WTh,
                                             const unsigned short* __restrict__ WTl,
                                             const float* __restrict__ bias,
                                             float* __restrict__ out_t,
                                             float* __restrict__ R) {
  __shared__ char smem[34816];          // [0,1K): knn | [1K,17K): XeH | [17K,33K): XeL ; phase3: float S[256][33]
  int* knn_s = (int*)smem;
  __bf16* XeH = (__bf16*)(smem + 1024);
  __bf16* XeL = (__bf16*)(smem + 17408);
  const int b = blockIdx.y;
  const int m0 = blockIdx.x * 32;
  const int t = threadIdx.x, w = t >> 6, lane = t & 63;
  const int l31 = lane & 31, lh = lane >> 5;

  knn_s[t] = knn[((long)b * NT + m0 + (t >> 3)) * KI + (t & 7)];
  __syncthreads();

  const int n = t & 31, cg = t >> 5;    // node, channel-group of 32
  int idx[KI];
#pragma unroll
  for (int q = 0; q < KI; ++q) idx[q] = knn_s[n * KI + q];
  const float* trow = R + ((long)b * NT + m0 + n) * CH;     // Xn_t row (in-place source)
  const float* cb = Xn_c + (long)b * NCTX * CH;
#pragma unroll
  for (int kk = 0; kk < 4; ++kk) {
    const int c = cg * 32 + kk * 8;
    float xe[8];
    float4 a0 = *(const float4*)(trow + c);
    float4 a1 = *(const float4*)(trow + c + 4);
    xe[0]=a0.x; xe[1]=a0.y; xe[2]=a0.z; xe[3]=a0.w;
    xe[4]=a1.x; xe[5]=a1.y; xe[6]=a1.z; xe[7]=a1.w;
#pragma unroll
    for (int q = 0; q < KI; ++q) {
      const float* crow = cb + (long)idx[q] * CH + c;
      float4 c0 = *(const float4*)(crow);
      float4 c1 = *(const float4*)(crow + 4);
      xe[0]+=c0.x; xe[1]+=c0.y; xe[2]+=c0.z; xe[3]+=c0.w;
      xe[4]+=c1.x; xe[5]+=c1.y; xe[6]+=c1.z; xe[7]+=c1.w;
    }
    unsigned h8[8], l8[8];
#pragma unroll
    for (int e = 0; e < 8; ++e) {
      float v = xe[e] / 9.0f;
      unsigned short h = bf16_rne(v);
      h8[e] = h;
      float hf = __uint_as_float((unsigned)h << 16);
      l8[e] = bf16_rne(v - hf);
    }
    const int k8 = cg * 4 + kk;
    const int off = (k8 >> 1) * 512 + ((k8 & 1) * 32 + n) * 8;   // fragment-linear
    uint4 ph, pl;
    ph.x = h8[0] | (h8[1] << 16); ph.y = h8[2] | (h8[3] << 16);
    ph.z = h8[4] | (h8[5] << 16); ph.w = h8[6] | (h8[7] << 16);
    pl.x = l8[0] | (l8[1] << 16); pl.y = l8[2] | (l8[3] << 16);
    pl.z = l8[4] | (l8[5] << 16); pl.w = l8[6] | (l8[7] << 16);
    *(uint4*)(XeH + off) = ph;
    *(uint4*)(XeL + off) = pl;
  }
  __syncthreads();

  const unsigned short* wh0 = WTh + (long)(w * 64 + l31) * CH;
  const unsigned short* wl0 = WTl + (long)(w * 64 + l31) * CH;
  f32x16 acc0, acc1;
#pragma unroll
  for (int i = 0; i < 16; ++i) { acc0[i] = 0.f; acc1[i] = 0.f; }
#pragma unroll
  for (int s = 0; s < 16; ++s) {
    const int koff = lh * 8 + s * 16;
    bf16x8 beh = *(const bf16x8*)&XeH[s * 512 + lane * 8];
    bf16x8 bel = *(const bf16x8*)&XeL[s * 512 + lane * 8];
    bf16x8 ah0 = *(const bf16x8*)(const __bf16*)(wh0 + koff);
    bf16x8 al0 = *(const bf16x8*)(const __bf16*)(wl0 + koff);
    bf16x8 ah1 = *(const bf16x8*)(const __bf16*)(wh0 + 32 * CH + koff);
    bf16x8 al1 = *(const bf16x8*)(const __bf16*)(wl0 + 32 * CH + koff);
    acc0 = __builtin_amdgcn_mfma_f32_32x32x16_bf16(ah0, beh, acc0, 0, 0, 0);
    acc1 = __builtin_amdgcn_mfma_f32_32x32x16_bf16(ah1, beh, acc1, 0, 0, 0);
    acc0 = __builtin_amdgcn_mfma_f32_32x32x16_bf16(al0, beh, acc0, 0, 0, 0);
    acc1 = __builtin_amdgcn_mfma_f32_32x32x16_bf16(al1, beh, acc1, 0, 0, 0);
    acc0 = __builtin_amdgcn_mfma_f32_32x32x16_bf16(ah0, bel, acc0, 0, 0, 0);
    acc1 = __builtin_amdgcn_mfma_f32_32x32x16_bf16(ah1, bel, acc1, 0, 0, 0);
  }
  __syncthreads();   // all XeH/XeL reads done; smem reusable

  float* S = (float*)smem;               // [256][33]
  float* ot = out_t + (long)b * CH * NT + m0;
#pragma unroll
  for (int reg = 0; reg < 16; ++reg) {
    const int row = (reg & 3) + 8 * (reg >> 2) + 4 * lh;
    const int ch0 = w * 64 + row, ch1 = ch0 + 32;
    float v0 = acc0[reg] + bias[ch0];
    float v1 = acc1[reg] + bias[ch1];
    S[ch0 * 33 + l31] = v0;
    S[ch1 * 33 + l31] = v1;
    ot[(long)ch0 * NT + l31] = v0;       // coalesced image-layout store
    ot[(long)ch1 * NT + l31] = v1;
  }
  __syncthreads();
  float* rrow = R + ((long)b * NT + m0 + n) * CH;
#pragma unroll
  for (int kk = 0; kk < 8; ++kk) {
    const int c = cg * 32 + kk * 4;
    float4 v;
    v.x = S[(c + 0) * 33 + n];
    v.y = S[(c + 1) * 33 + n];
    v.z = S[(c + 2) * 33 + n];
    v.w = S[(c + 3) * 33 + n];
    *(float4*)(rrow + c) = v;
  }
}

// ---------------- scatter-add contributions to context nodes ----------------
__global__ __launch_bounds__(256) void k_scatter(const float* __restrict__ Xet,
                                                 const int* __restrict__ knn,
                                                 float* __restrict__ contrib) {
  const int n = blockIdx.x, b = blockIdx.y, c = threadIdx.x;
  const float v = Xet[((long)b * NT + n) * CH + c];
  const int* kn = knn + ((long)b * NT + n) * KI;
#pragma unroll
  for (int q = 0; q < KI; ++q)
    atomicAdd(&contrib[((long)b * NCTX + kn[q]) * CH + c], v);
}

// ---------------- finalize context outputs: divide by counts, transpose, split ----------------
__global__ __launch_bounds__(256) void k_fin_c(const float* __restrict__ contrib,
                                               const unsigned* __restrict__ counts,
                                               float* __restrict__ out1,
                                               float* __restrict__ out2) {
  __shared__ float tile[32][33];
  const int b = blockIdx.z;
  const int j0 = blockIdx.x * 32, c0 = blockIdx.y * 32;
  const int tx = threadIdx.x, ty = threadIdx.y;
#pragma unroll
  for (int i = ty; i < 32; i += 8) {
    float cnt = fmaxf((float)counts[(long)b * NCTX + j0 + i], 1.0f);
    tile[i][tx] = contrib[((long)b * NCTX + j0 + i) * CH + c0 + tx] / cnt;
  }
  __syncthreads();
  float* outp = (j0 < NT) ? (out1 + (long)b * CH * NT + j0)
                          : (out2 + (long)b * CH * NT + (j0 - NT));
#pragma unroll
  for (int i = ty; i < 32; i += 8)
    outp[(long)(c0 + i) * NT + tx] = tile[tx][i];
}

extern "C" void kernel_launch(void* const* d_in, const int* in_sizes, int n_in,
                              void* d_out, int out_size, void* d_ws, size_t ws_size,
                              hipStream_t stream) {
  const float* Xt  = (const float*)d_in[0];
  const float* Xc1 = (const float*)d_in[1];
  const float* Xc2 = (const float*)d_in[2];
  const float* W1  = (const float*)d_in[3];
  const float* b1  = (const float*)d_in[4];
  const float* W2  = (const float*)d_in[5];
  const float* b2  = (const float*)d_in[6];
  float* out = (float*)d_out;

  float* P = (float*)d_ws;
  float* Q = P + (long)BATCH * NCTX * CH;
  float* R = Q + (long)BATCH * NT * CH;
  float* nrm = R + (long)BATCH * NT * CH;
  unsigned* counts = (unsigned*)(nrm + (long)BATCH * NCTX);
  int* knn = (int*)(counts + (long)BATCH * NCTX);
  unsigned short* WT1h = (unsigned short*)(knn + (long)BATCH * NT * KI);
  unsigned short* WT1l = WT1h + CH * CH;
  unsigned short* WT2h = WT1l + CH * CH;
  unsigned short* WT2l = WT2h + CH * CH;

  unsigned* cand = (unsigned*)R;   // dead before gemm1 writes Xn_t to R

  unsigned short* XcBh = (unsigned short*)d_out;
  unsigned short* XtBh = XcBh + (long)BATCH * NCTX * CH;
  unsigned short* XcBl = XtBh + (long)BATCH * NT * CH;
  unsigned short* XtBl = XcBl + (long)BATCH * NCTX * CH;

  float* Xn_c = P;
  float* Xn_t = R;

  float* out_t  = out;             // overwrites dead XcBh region (after gemm1 reads)
  float* out_c1 = out + (long)BATCH * CH * NT;
  float* out_c2 = out + 2L * BATCH * CH * NT;

  dim3 tb(32, 8);

  hipMemsetAsync(nrm, 0, (size_t)BATCH * NCTX * 8, stream);   // nrm + counts

  k_wtrans<<<dim3(8, 8, 2), tb, 0, stream>>>(W1, W2, WT1h, WT1l, WT2h, WT2l);

  k_transpose2<<<dim3(NT / 32, CH / 64, 12), tb, 0, stream>>>(
      Xt, Xc1, Xc2, Q, P, XtBh, XtBl, XcBh, XcBl, nrm);

  k_dist_mfma<<<dim3(1024), 256, 0, stream>>>(
      (const __bf16*)XcBh, (const __bf16*)XtBh, nrm, cand);

  k_rescore<<<dim3(NT, BATCH), 64, 0, stream>>>(Q, P, cand, knn, counts);

  // node2edge linear (bf16 MFMA, 3-term): Xn_t -> R, Xn_c -> P
  k_gemm_mfma<<<dim3(NT / 32, BATCH), 256, 0, stream>>>(XtBh, XtBl, WT1h, WT1l, b1, Xn_t, NT);
  k_gemm_mfma<<<dim3(NCTX / 32, BATCH), 256, 0, stream>>>(XcBh, XcBl, WT1h, WT1l, b1, Xn_c, NCTX);

  // fused gather + edge2node + out_t + X_et rows (in-place on R)
  k_gg2<<<dim3(NT / 32, BATCH), 256, 0, stream>>>(Xn_c, knn, WT2h, WT2l, b2, out_t, R);

  // context scatter-mean (P dead after k_gg2 -> contrib)
  hipMemsetAsync(P, 0, (size_t)BATCH * NCTX * CH * 4, stream);
  k_scatter<<<dim3(NT, BATCH), 256, 0, stream>>>(R, knn, P);
  k_fin_c<<<dim3(NCTX / 32, CH / 32, BATCH), tb, 0, stream>>>(P, counts, out_c1, out_c2);
}

// Round 9
// 473.376 us; speedup vs baseline: 1.0230x; 1.0230x over previous
//
#include <hip/hip_runtime.h>
#include <math.h>
#include <float.h>

#define BATCH 4
#define CH    256
#define NT    4096
#define NCTX  8192
#define KI    8

// coarse-selection geometry
#define CSEL    10                 // per-split top-C after lane-half merge (>=8+2 slack => safe)
#define DNSPLIT 16                 // ctx splits (occupancy fill: 2048 blocks, 5/CU by LDS)
#define CTX_PER (NCTX / DNSPLIT)   // 512
#define NTILE   (CTX_PER / 32)     // 16 tiles of 32 ctx
#define NKEY    (DNSPLIT * CSEL)   // 160 packed keys per target
#define RESC    12                 // keys kept for exact fp64 rescore

typedef __attribute__((ext_vector_type(8)))  __bf16 bf16x8;
typedef __attribute__((ext_vector_type(16))) float  f32x16;

__device__ __forceinline__ unsigned short bf16_rne(float v) {
  unsigned u = __float_as_uint(v);
  return (unsigned short)((u + 0x7fffu + ((u >> 16) & 1u)) >> 16);
}

// ---------------- merged transpose: [CH][NT] -> [NT][CH] fp32 + bf16 hi/lo, + ctx norms ----------------
__global__ __launch_bounds__(256) void k_transpose2(const float* __restrict__ Xt,
                                                    const float* __restrict__ Xc1,
                                                    const float* __restrict__ Xc2,
                                                    float* __restrict__ Q,
                                                    float* __restrict__ P,
                                                    unsigned short* __restrict__ XtBh,
                                                    unsigned short* __restrict__ XtBl,
                                                    unsigned short* __restrict__ XcBh,
                                                    unsigned short* __restrict__ XcBl,
                                                    float* __restrict__ nrm) {
  __shared__ float tile[64][33];
  __shared__ float ps[8][32];
  const int which = blockIdx.z >> 2, b = blockIdx.z & 3;
  const float* src;
  float* dF; unsigned short *dH, *dL; float* nrmp = nullptr;
  if (which == 0) {
    src = Xt + (long)b * CH * NT;
    dF = Q + (long)b * NT * CH;
    dH = XtBh + (long)b * NT * CH;  dL = XtBl + (long)b * NT * CH;
  } else if (which == 1) {
    src = Xc1 + (long)b * CH * NT;
    dF = P + (long)b * NCTX * CH;
    dH = XcBh + (long)b * NCTX * CH;  dL = XcBl + (long)b * NCTX * CH;
    nrmp = nrm + (long)b * NCTX;
  } else {
    src = Xc2 + (long)b * CH * NT;
    dF = P + ((long)b * NCTX + NT) * CH;
    dH = XcBh + ((long)b * NCTX + NT) * CH;  dL = XcBl + ((long)b * NCTX + NT) * CH;
    nrmp = nrm + (long)b * NCTX + NT;
  }
  const int m0 = blockIdx.x * 32, c0 = blockIdx.y * 64;
  const int tx = threadIdx.x, ty = threadIdx.y;
  float part = 0.f;
#pragma unroll
  for (int i = ty; i < 64; i += 8) {
    float v = src[(long)(c0 + i) * NT + (m0 + tx)];
    tile[i][tx] = v;
    part = fmaf(v, v, part);
  }
  if (which) ps[ty][tx] = part;
  __syncthreads();
#pragma unroll
  for (int i = ty; i < 32; i += 8) {
    float v0 = tile[2 * tx][i];
    float v1 = tile[2 * tx + 1][i];
    long o = (long)(m0 + i) * CH + (c0 + 2 * tx);
    float2 f2; f2.x = v0; f2.y = v1;
    *(float2*)&dF[o] = f2;
    unsigned short h0 = bf16_rne(v0), h1 = bf16_rne(v1);
    ushort2 h2; h2.x = h0; h2.y = h1;
    *(ushort2*)&dH[o] = h2;
    float hf0 = __uint_as_float((unsigned)h0 << 16);
    float hf1 = __uint_as_float((unsigned)h1 << 16);
    ushort2 l2; l2.x = bf16_rne(v0 - hf0); l2.y = bf16_rne(v1 - hf1);
    *(ushort2*)&dL[o] = l2;
  }
  if (which && ty == 0) {
    float s = 0.f;
#pragma unroll
    for (int j = 0; j < 8; ++j) s += ps[j][tx];
    atomicAdd(&nrmp[m0 + tx], -0.5f * s);
  }
}

// ---------------- W transpose: fp32 [CH(k)][CH(n)] -> bf16 hi/lo WT[n][k]; z = which W ----------------
__global__ __launch_bounds__(256) void k_wtrans(const float* __restrict__ W1,
                                                const float* __restrict__ W2,
                                                unsigned short* __restrict__ WT1h,
                                                unsigned short* __restrict__ WT1l,
                                                unsigned short* __restrict__ WT2h,
                                                unsigned short* __restrict__ WT2l) {
  __shared__ float tile[32][33];
  const float* W = blockIdx.z ? W2 : W1;
  unsigned short* WTh = blockIdx.z ? WT2h : WT1h;
  unsigned short* WTl = blockIdx.z ? WT2l : WT1l;
  const int n0 = blockIdx.x * 32, k0 = blockIdx.y * 32;
  const int tx = threadIdx.x, ty = threadIdx.y;
#pragma unroll
  for (int i = ty; i < 32; i += 8)
    tile[i][tx] = W[(k0 + i) * CH + (n0 + tx)];
  __syncthreads();
#pragma unroll
  for (int i = ty; i < 32; i += 8) {
    float v = tile[tx][i];
    int o = (n0 + i) * CH + (k0 + tx);
    unsigned short h = bf16_rne(v);
    WTh[o] = h;
    float hf = __uint_as_float((unsigned)h << 16);
    WTl[o] = bf16_rne(v - hf);
  }
}

// ---------------- MFMA coarse scorer + per-lane top-CSEL (unguarded bubble), DNSPLIT=16 ----------------
// 1D XCD-swizzled grid of 2048: lid = (b*2+jh) + 8*(jw + 16*split); XCD(lid)=lid%8 owns one
// (batch, j-half); split slowest -> small per-XCD L2 set. 5 blocks/CU by LDS (32 KB).
// C/D layout: col = lane&31 (target), row = (reg&3) + 8*(reg>>2) + 4*(lane>>5) (ctx).
// acc init with -0.5*|c|^2 so score = -2*acc + 512 = d^2 - |t|^2 + 512 > 0 (split-independent).
// key = (bits(score)&~0x7FF) | local_ctx_idx (9 bits used).
__global__ __launch_bounds__(256) void k_dist_mfma(const __bf16* __restrict__ XcB,
                                                   const __bf16* __restrict__ XtB,
                                                   const float* __restrict__ nrm,
                                                   unsigned* __restrict__ cand) {
  __shared__ __bf16 lds[2][32 * CH];   // 2 x 16 KB ctx tiles, fragment-linear order
  const int lid = blockIdx.x;
  const int xk = lid & 7;
  const int b = xk >> 1, jh = xk & 1;
  const int jw = (lid >> 3) & 15, split = lid >> 7;
  const int t = threadIdx.x, w = t >> 6, lane = t & 63;
  const int l31 = lane & 31, lh = lane >> 5;
  const int tgt0 = (jh * 16 + jw) * 128 + w * 32;
  const int cbase = split * CTX_PER;
  const float* nrmt = nrm + (long)b * NCTX + cbase;   // -0.5*|c|^2

  const __bf16* tp = XtB + ((long)b * NT + tgt0 + l31) * CH + lh * 8;
  bf16x8 bfrag[16];
#pragma unroll
  for (int s = 0; s < 16; ++s) bfrag[s] = *(const bf16x8*)(tp + s * 16);

  unsigned kd[CSEL];
#pragma unroll
  for (int q = 0; q < CSEL; ++q) kd[q] = 0xFFFFFFFFu;

  const __bf16* cp = XcB + ((long)b * NCTX + cbase + l31) * CH;

  auto STAGE = [&](int buf, int jt) {
#pragma unroll
    for (int r = 0; r < 4; ++r) {
      int c = r * 4 + w;
      const __bf16* src = cp + (long)jt * 32 * CH + (c * 2 + lh) * 8;
      __bf16* dst = &lds[buf][c * 512];
      __builtin_amdgcn_global_load_lds((const __attribute__((address_space(1))) void*)src,
                                       (__attribute__((address_space(3))) void*)dst,
                                       16, 0, 0);
    }
  };

  STAGE(0, 0);
  __syncthreads();

  int cur = 0;
  for (int jt = 0; jt < NTILE; ++jt) {
    if (jt + 1 < NTILE) STAGE(cur ^ 1, jt + 1);

    const int ct0 = jt * 32;
    f32x16 acc;
#pragma unroll
    for (int g = 0; g < 4; ++g) {
      float4 nv = *(const float4*)&nrmt[ct0 + 8 * g + 4 * lh];
      acc[4 * g + 0] = nv.x; acc[4 * g + 1] = nv.y;
      acc[4 * g + 2] = nv.z; acc[4 * g + 3] = nv.w;
    }
#pragma unroll
    for (int s = 0; s < 16; ++s) {
      bf16x8 a = *(const bf16x8*)(&lds[cur][s * 512 + lane * 8]);
      acc = __builtin_amdgcn_mfma_f32_32x32x16_bf16(a, bfrag[s], acc, 0, 0, 0);
    }

#pragma unroll
    for (int reg = 0; reg < 16; ++reg) {
      const int row = (reg & 3) + 8 * (reg >> 2) + lh * 4;
      float sc = fmaf(acc[reg], -2.0f, 512.0f);
      unsigned key = (__float_as_uint(sc) & 0xFFFFF800u) | (unsigned)ct0 | (unsigned)row;
#pragma unroll
      for (int q = 0; q < CSEL; ++q) {   // branchless sorted-ascending bubble insert
        unsigned lo = min(key, kd[q]);
        key = max(key, kd[q]);
        kd[q] = lo;
      }
    }
    __syncthreads();
    cur ^= 1;
  }

  // merge the two lane-half sorted lists: lowest-CSEL of union = min(A[q], B[CSEL-1-q])
  unsigned oth[CSEL];
#pragma unroll
  for (int q = 0; q < CSEL; ++q) oth[q] = (unsigned)__shfl_xor((int)kd[q], 32, 64);
  if (lh == 0) {
    long ob = (((long)b * NT + tgt0 + l31) * DNSPLIT + split) * CSEL;
#pragma unroll
    for (int q = 0; q < CSEL; ++q)
      cand[ob + q] = min(kd[q], oth[CSEL - 1 - q]);   // raw key
  }
}

// ---------------- rescore: coarse top-RESC of 160 keys, fp64 exact, rank-8 + counts ----------------
__global__ __launch_bounds__(64) void k_rescore(const float* __restrict__ XtT,
                                                const float* __restrict__ XcT,
                                                const unsigned* __restrict__ cand,
                                                int* __restrict__ knn,
                                                unsigned* __restrict__ counts) {
  const int n = blockIdx.x, b = blockIdx.y, lane = threadIdx.x;
  const int grp = lane >> 4, gl = lane & 15;
  __shared__ unsigned sk[NKEY];
  __shared__ int cidx[RESC];
  __shared__ double sd[RESC];
  __shared__ int sj[RESC];
  const unsigned* kp = cand + ((long)b * NT + n) * NKEY;
  unsigned k0 = kp[lane];
  unsigned k1 = kp[64 + lane];
  unsigned k2 = (lane < NKEY - 128) ? kp[128 + lane] : 0xFFFFFFFFu;
  sk[lane] = k0;
  sk[64 + lane] = k1;
  if (lane < NKEY - 128) sk[128 + lane] = k2;
  __syncthreads();
  int r0 = 0, r1 = 0, r2 = 0;
  for (int i = 0; i < NKEY; ++i) {
    unsigned s = sk[i];
    r0 += (s < k0 || (s == k0 && i < lane)) ? 1 : 0;
    r1 += (s < k1 || (s == k1 && i < 64 + lane)) ? 1 : 0;
    r2 += (s < k2 || (s == k2 && i < 128 + lane)) ? 1 : 0;
  }
  if (r0 < RESC) cidx[r0] = (lane / CSEL) * CTX_PER + (int)(k0 & 0x7FFu);
  if (r1 < RESC) cidx[r1] = ((64 + lane) / CSEL) * CTX_PER + (int)(k1 & 0x7FFu);
  if (lane < NKEY - 128 && r2 < RESC)
    cidx[r2] = ((128 + lane) / CSEL) * CTX_PER + (int)(k2 & 0x7FFu);
  __syncthreads();

  const float* xt = XtT + ((long)b * NT + n) * CH + gl * 16;
  double xa[16];
#pragma unroll
  for (int r = 0; r < 4; ++r) {
    float4 v = *(const float4*)(xt + r * 4);
    xa[4 * r + 0] = (double)v.x; xa[4 * r + 1] = (double)v.y;
    xa[4 * r + 2] = (double)v.z; xa[4 * r + 3] = (double)v.w;
  }
#pragma unroll
  for (int q0 = 0; q0 < RESC; q0 += 4) {
    int q = q0 + grp;
    int j = cidx[q];
    const float* xc = XcT + ((long)b * NCTX + j) * CH + gl * 16;
    double acc = 0.0;
#pragma unroll
    for (int r = 0; r < 4; ++r) {
      float4 v = *(const float4*)(xc + r * 4);
      double d0 = xa[4 * r + 0] - (double)v.x; acc = fma(d0, d0, acc);
      double d1 = xa[4 * r + 1] - (double)v.y; acc = fma(d1, d1, acc);
      double d2 = xa[4 * r + 2] - (double)v.z; acc = fma(d2, d2, acc);
      double d3 = xa[4 * r + 3] - (double)v.w; acc = fma(d3, d3, acc);
    }
#pragma unroll
    for (int off = 8; off > 0; off >>= 1) acc += __shfl_xor(acc, off, 64);
    if (gl == 0) { sd[q] = acc; sj[q] = j; }
  }
  __syncthreads();
  double dq = (lane < RESC) ? sd[lane] : DBL_MAX;
  int    jq = (lane < RESC) ? sj[lane] : 0x7fffffff;
  int rank = 0;
#pragma unroll
  for (int i = 0; i < RESC; ++i) {
    double di = sd[i]; int ji = sj[i];
    rank += (di < dq || (di == dq && ji < jq)) ? 1 : 0;
  }
  if (lane < RESC && rank < KI) {
    knn[((long)b * NT + n) * KI + rank] = jq;
    atomicAdd(&counts[(long)b * NCTX + jq], 1u);
  }
}

// ---------------- bf16 MFMA GEMM + bias, 3-term hi/lo split ----------------
__global__ __launch_bounds__(256) void k_gemm_mfma(const unsigned short* __restrict__ Ah,
                                                   const unsigned short* __restrict__ Al,
                                                   const unsigned short* __restrict__ WTh,
                                                   const unsigned short* __restrict__ WTl,
                                                   const float* __restrict__ bias,
                                                   float* __restrict__ out, int M) {
  __shared__ __bf16 ldsH[32 * CH];
  __shared__ __bf16 ldsL[32 * CH];
  const int b = blockIdx.y;
  const int m0 = blockIdx.x * 32;
  const int t = threadIdx.x, w = t >> 6, lane = t & 63;
  const int l31 = lane & 31, lh = lane >> 5;
  const long abase = (long)b * M * CH;
  const unsigned short* pH = Ah + abase + (long)(m0 + l31) * CH;
  const unsigned short* pL = Al + abase + (long)(m0 + l31) * CH;
#pragma unroll
  for (int r = 0; r < 4; ++r) {
    int c = r * 4 + w;
    __builtin_amdgcn_global_load_lds(
        (const __attribute__((address_space(1))) void*)(pH + (c * 2 + lh) * 8),
        (__attribute__((address_space(3))) void*)&ldsH[c * 512], 16, 0, 0);
    __builtin_amdgcn_global_load_lds(
        (const __attribute__((address_space(1))) void*)(pL + (c * 2 + lh) * 8),
        (__attribute__((address_space(3))) void*)&ldsL[c * 512], 16, 0, 0);
  }
  __syncthreads();

  const int n0 = w * 64;
  f32x16 acc0, acc1;
#pragma unroll
  for (int i = 0; i < 16; ++i) { acc0[i] = 0.f; acc1[i] = 0.f; }
#pragma unroll
  for (int s = 0; s < 16; ++s) {
    bf16x8 ah = *(const bf16x8*)&ldsH[s * 512 + lane * 8];
    bf16x8 al = *(const bf16x8*)&ldsL[s * 512 + lane * 8];
    const int koff = lh * 8 + s * 16;
    bf16x8 bh0 = *(const bf16x8*)&WTh[(n0 + l31) * CH + koff];
    bf16x8 bl0 = *(const bf16x8*)&WTl[(n0 + l31) * CH + koff];
    bf16x8 bh1 = *(const bf16x8*)&WTh[(n0 + 32 + l31) * CH + koff];
    bf16x8 bl1 = *(const bf16x8*)&WTl[(n0 + 32 + l31) * CH + koff];
    acc0 = __builtin_amdgcn_mfma_f32_32x32x16_bf16(ah, bh0, acc0, 0, 0, 0);
    acc1 = __builtin_amdgcn_mfma_f32_32x32x16_bf16(ah, bh1, acc1, 0, 0, 0);
    acc0 = __builtin_amdgcn_mfma_f32_32x32x16_bf16(ah, bl0, acc0, 0, 0, 0);
    acc1 = __builtin_amdgcn_mfma_f32_32x32x16_bf16(ah, bl1, acc1, 0, 0, 0);
    acc0 = __builtin_amdgcn_mfma_f32_32x32x16_bf16(al, bh0, acc0, 0, 0, 0);
    acc1 = __builtin_amdgcn_mfma_f32_32x32x16_bf16(al, bh1, acc1, 0, 0, 0);
  }
  float* ob = out + abase;
  float bi0 = bias[n0 + l31], bi1 = bias[n0 + 32 + l31];
#pragma unroll
  for (int reg = 0; reg < 16; ++reg) {
    int row = (reg & 3) + 8 * (reg >> 2) + 4 * lh;
    ob[(long)(m0 + row) * CH + n0 + l31]      = acc0[reg] + bi0;
    ob[(long)(m0 + row) * CH + n0 + 32 + l31] = acc1[reg] + bi1;
  }
}

// ---------------- gather-mean: X_edge = (Xn_t + sum_k Xn_c[knn]) / 9 -> bf16 hi/lo ----------------
__global__ __launch_bounds__(256) void k_gather(const float* __restrict__ Xn_t,
                                                const float* __restrict__ Xn_c,
                                                const int* __restrict__ knn,
                                                unsigned short* __restrict__ XeH,
                                                unsigned short* __restrict__ XeL) {
  const int n = blockIdx.x, b = blockIdx.y, c = threadIdx.x;
  const int* kn = knn + ((long)b * NT + n) * KI;
  int j[KI];
#pragma unroll
  for (int q = 0; q < KI; ++q) j[q] = kn[q];
  float acc = Xn_t[((long)b * NT + n) * CH + c];
#pragma unroll
  for (int q = 0; q < KI; ++q) acc += Xn_c[((long)b * NCTX + j[q]) * CH + c];
  float xe = acc / 9.0f;
  long o = ((long)b * NT + n) * CH + c;
  unsigned short h = bf16_rne(xe);
  XeH[o] = h;
  float hf = __uint_as_float((unsigned)h << 16);
  XeL[o] = bf16_rne(xe - hf);
}

// ---------------- scatter-add contributions to context nodes ----------------
__global__ __launch_bounds__(256) void k_scatter(const float* __restrict__ Xet,
                                                 const int* __restrict__ knn,
                                                 float* __restrict__ contrib) {
  const int n = blockIdx.x, b = blockIdx.y, c = threadIdx.x;
  const float v = Xet[((long)b * NT + n) * CH + c];
  const int* kn = knn + ((long)b * NT + n) * KI;
#pragma unroll
  for (int q = 0; q < KI; ++q)
    atomicAdd(&contrib[((long)b * NCTX + kn[q]) * CH + c], v);
}

// ---------------- finalize target output: transpose [NT][CH] -> image [CH][NT] ----------------
__global__ __launch_bounds__(256) void k_fin_t(const float* __restrict__ Xet,
                                               float* __restrict__ out) {
  __shared__ float tile[32][33];
  const int b = blockIdx.z;
  const int n0 = blockIdx.x * 32, c0 = blockIdx.y * 32;
  const int tx = threadIdx.x, ty = threadIdx.y;
#pragma unroll
  for (int i = ty; i < 32; i += 8)
    tile[i][tx] = Xet[((long)b * NT + n0 + i) * CH + c0 + tx];
  __syncthreads();
#pragma unroll
  for (int i = ty; i < 32; i += 8)
    out[((long)b * CH + c0 + i) * NT + n0 + tx] = tile[tx][i];
}

// ---------------- finalize context outputs: divide by counts, transpose, split ----------------
__global__ __launch_bounds__(256) void k_fin_c(const float* __restrict__ contrib,
                                               const unsigned* __restrict__ counts,
                                               float* __restrict__ out1,
                                               float* __restrict__ out2) {
  __shared__ float tile[32][33];
  const int b = blockIdx.z;
  const int j0 = blockIdx.x * 32, c0 = blockIdx.y * 32;
  const int tx = threadIdx.x, ty = threadIdx.y;
#pragma unroll
  for (int i = ty; i < 32; i += 8) {
    float cnt = fmaxf((float)counts[(long)b * NCTX + j0 + i], 1.0f);
    tile[i][tx] = contrib[((long)b * NCTX + j0 + i) * CH + c0 + tx] / cnt;
  }
  __syncthreads();
  float* outp = (j0 < NT) ? (out1 + (long)b * CH * NT + j0)
                          : (out2 + (long)b * CH * NT + (j0 - NT));
#pragma unroll
  for (int i = ty; i < 32; i += 8)
    outp[(long)(c0 + i) * NT + tx] = tile[tx][i];
}

extern "C" void kernel_launch(void* const* d_in, const int* in_sizes, int n_in,
                              void* d_out, int out_size, void* d_ws, size_t ws_size,
                              hipStream_t stream) {
  const float* Xt  = (const float*)d_in[0];
  const float* Xc1 = (const float*)d_in[1];
  const float* Xc2 = (const float*)d_in[2];
  const float* W1  = (const float*)d_in[3];
  const float* b1  = (const float*)d_in[4];
  const float* W2  = (const float*)d_in[5];
  const float* b2  = (const float*)d_in[6];
  float* out = (float*)d_out;

  float* P = (float*)d_ws;
  float* Q = P + (long)BATCH * NCTX * CH;
  float* R = Q + (long)BATCH * NT * CH;
  float* nrm = R + (long)BATCH * NT * CH;
  unsigned* counts = (unsigned*)(nrm + (long)BATCH * NCTX);
  int* knn = (int*)(counts + (long)BATCH * NCTX);
  unsigned short* WT1h = (unsigned short*)(knn + (long)BATCH * NT * KI);
  unsigned short* WT1l = WT1h + CH * CH;
  unsigned short* WT2h = WT1l + CH * CH;
  unsigned short* WT2l = WT2h + CH * CH;

  unsigned* cand = (unsigned*)R;   // 10.5 MB (B*NT*160*4), dead before gemm1 writes Xn_t to R

  unsigned short* XcBh = (unsigned short*)d_out;
  unsigned short* XtBh = XcBh + (long)BATCH * NCTX * CH;
  unsigned short* XcBl = XtBh + (long)BATCH * NT * CH;
  unsigned short* XtBl = XcBl + (long)BATCH * NCTX * CH;

  float* Xn_c = P;
  float* Xn_t = R;
  unsigned short* XeH = (unsigned short*)Q;   // after rescore, Q (XtT) is dead
  unsigned short* XeL = XeH + (long)BATCH * NT * CH;

  float* out_t  = out;             // overwrites dead XcBh region (after gemm1 reads)
  float* out_c1 = out + (long)BATCH * CH * NT;
  float* out_c2 = out + 2L * BATCH * CH * NT;

  dim3 tb(32, 8);

  hipMemsetAsync(nrm, 0, (size_t)BATCH * NCTX * 8, stream);   // nrm + counts

  k_wtrans<<<dim3(8, 8, 2), tb, 0, stream>>>(W1, W2, WT1h, WT1l, WT2h, WT2l);

  k_transpose2<<<dim3(NT / 32, CH / 64, 12), tb, 0, stream>>>(
      Xt, Xc1, Xc2, Q, P, XtBh, XtBl, XcBh, XcBl, nrm);

  k_dist_mfma<<<dim3(8 * 16 * DNSPLIT), 256, 0, stream>>>(
      (const __bf16*)XcBh, (const __bf16*)XtBh, nrm, cand);

  k_rescore<<<dim3(NT, BATCH), 64, 0, stream>>>(Q, P, cand, knn, counts);

  // node2edge linear (bf16 MFMA, 3-term): Xn_t -> R, Xn_c -> P
  k_gemm_mfma<<<dim3(NT / 32, BATCH), 256, 0, stream>>>(XtBh, XtBl, WT1h, WT1l, b1, Xn_t, NT);
  k_gemm_mfma<<<dim3(NCTX / 32, BATCH), 256, 0, stream>>>(XcBh, XcBl, WT1h, WT1l, b1, Xn_c, NCTX);

  // edge mean-pool -> Q as bf16 hi/lo
  k_gather<<<dim3(NT, BATCH), 256, 0, stream>>>(Xn_t, Xn_c, knn, XeH, XeL);

  // edge2node linear: X_et -> R
  k_gemm_mfma<<<dim3(NT / 32, BATCH), 256, 0, stream>>>(XeH, XeL, WT2h, WT2l, b2, R, NT);

  // out_t (overwrites dead XcBh region of d_out)
  k_fin_t<<<dim3(NT / 32, CH / 32, BATCH), tb, 0, stream>>>(R, out_t);

  // context scatter-mean (P dead after gather -> contrib)
  hipMemsetAsync(P, 0, (size_t)BATCH * NCTX * CH * 4, stream);
  k_scatter<<<dim3(NT, BATCH), 256, 0, stream>>>(R, knn, P);
  k_fin_c<<<dim3(NCTX / 32, CH / 32, BATCH), tb, 0, stream>>>(P, counts, out_c1, out_c2);
}

// Round 10
// 467.493 us; speedup vs baseline: 1.0359x; 1.0126x over previous
//
#include <hip/hip_runtime.h>
#include <math.h>
#include <float.h>

#define BATCH 4
#define CH    256
#define NT    4096
#define NCTX  8192
#define KI    8

// coarse-selection geometry
#define CSEL    10                 // per-split top-C after lane-half merge (>=8+2 slack => safe)
#define DNSPLIT 8                  // ctx splits
#define CTX_PER (NCTX / DNSPLIT)   // 1024
#define NTILE   (CTX_PER / 32)     // 32 tiles of 32 ctx
#define NKEY    (DNSPLIT * CSEL)   // 80 packed keys per target
#define RESC    12                 // keys kept for exact fp64 rescore

typedef __attribute__((ext_vector_type(8)))  __bf16 bf16x8;
typedef __attribute__((ext_vector_type(16))) float  f32x16;

__device__ __forceinline__ unsigned short bf16_rne(float v) {
  unsigned u = __float_as_uint(v);
  return (unsigned short)((u + 0x7fffu + ((u >> 16) & 1u)) >> 16);
}

// ---------------- merged transpose: [CH][NT] -> [NT][CH] fp32 + bf16 hi/lo, + ctx norms ----------------
__global__ __launch_bounds__(256) void k_transpose2(const float* __restrict__ Xt,
                                                    const float* __restrict__ Xc1,
                                                    const float* __restrict__ Xc2,
                                                    float* __restrict__ Q,
                                                    float* __restrict__ P,
                                                    unsigned short* __restrict__ XtBh,
                                                    unsigned short* __restrict__ XtBl,
                                                    unsigned short* __restrict__ XcBh,
                                                    unsigned short* __restrict__ XcBl,
                                                    float* __restrict__ nrm) {
  __shared__ float tile[64][33];
  __shared__ float ps[8][32];
  const int which = blockIdx.z >> 2, b = blockIdx.z & 3;
  const float* src;
  float* dF; unsigned short *dH, *dL; float* nrmp = nullptr;
  if (which == 0) {
    src = Xt + (long)b * CH * NT;
    dF = Q + (long)b * NT * CH;
    dH = XtBh + (long)b * NT * CH;  dL = XtBl + (long)b * NT * CH;
  } else if (which == 1) {
    src = Xc1 + (long)b * CH * NT;
    dF = P + (long)b * NCTX * CH;
    dH = XcBh + (long)b * NCTX * CH;  dL = XcBl + (long)b * NCTX * CH;
    nrmp = nrm + (long)b * NCTX;
  } else {
    src = Xc2 + (long)b * CH * NT;
    dF = P + ((long)b * NCTX + NT) * CH;
    dH = XcBh + ((long)b * NCTX + NT) * CH;  dL = XcBl + ((long)b * NCTX + NT) * CH;
    nrmp = nrm + (long)b * NCTX + NT;
  }
  const int m0 = blockIdx.x * 32, c0 = blockIdx.y * 64;
  const int tx = threadIdx.x, ty = threadIdx.y;
  float part = 0.f;
#pragma unroll
  for (int i = ty; i < 64; i += 8) {
    float v = src[(long)(c0 + i) * NT + (m0 + tx)];
    tile[i][tx] = v;
    part = fmaf(v, v, part);
  }
  if (which) ps[ty][tx] = part;
  __syncthreads();
#pragma unroll
  for (int i = ty; i < 32; i += 8) {
    float v0 = tile[2 * tx][i];
    float v1 = tile[2 * tx + 1][i];
    long o = (long)(m0 + i) * CH + (c0 + 2 * tx);
    float2 f2; f2.x = v0; f2.y = v1;
    *(float2*)&dF[o] = f2;
    unsigned short h0 = bf16_rne(v0), h1 = bf16_rne(v1);
    ushort2 h2; h2.x = h0; h2.y = h1;
    *(ushort2*)&dH[o] = h2;
    float hf0 = __uint_as_float((unsigned)h0 << 16);
    float hf1 = __uint_as_float((unsigned)h1 << 16);
    ushort2 l2; l2.x = bf16_rne(v0 - hf0); l2.y = bf16_rne(v1 - hf1);
    *(ushort2*)&dL[o] = l2;
  }
  if (which && ty == 0) {
    float s = 0.f;
#pragma unroll
    for (int j = 0; j < 8; ++j) s += ps[j][tx];
    atomicAdd(&nrmp[m0 + tx], -0.5f * s);
  }
}

// ---------------- W transpose: fp32 [CH(k)][CH(n)] -> bf16 hi/lo WT[n][k]; z = which W ----------------
__global__ __launch_bounds__(256) void k_wtrans(const float* __restrict__ W1,
                                                const float* __restrict__ W2,
                                                unsigned short* __restrict__ WT1h,
                                                unsigned short* __restrict__ WT1l,
                                                unsigned short* __restrict__ WT2h,
                                                unsigned short* __restrict__ WT2l) {
  __shared__ float tile[32][33];
  const float* W = blockIdx.z ? W2 : W1;
  unsigned short* WTh = blockIdx.z ? WT2h : WT1h;
  unsigned short* WTl = blockIdx.z ? WT2l : WT1l;
  const int n0 = blockIdx.x * 32, k0 = blockIdx.y * 32;
  const int tx = threadIdx.x, ty = threadIdx.y;
#pragma unroll
  for (int i = ty; i < 32; i += 8)
    tile[i][tx] = W[(k0 + i) * CH + (n0 + tx)];
  __syncthreads();
#pragma unroll
  for (int i = ty; i < 32; i += 8) {
    float v = tile[tx][i];
    int o = (n0 + i) * CH + (k0 + tx);
    unsigned short h = bf16_rne(v);
    WTh[o] = h;
    float hf = __uint_as_float((unsigned)h << 16);
    WTl[o] = bf16_rne(v - hf);
  }
}

// ---------------- MFMA coarse scorer + per-lane top-CSEL (unguarded bubble), XCD-swizzled ----------------
// lid = (b*2+jh) + 8*(jw + 16*split); XCD(lid)=lid%8 owns one (batch, j-half); split slowest.
// C/D layout: col = lane&31 (target), row = (reg&3) + 8*(reg>>2) + 4*(lane>>5) (ctx).
// acc init with -0.5*|c|^2 so score = -2*acc + 512 = d^2 - |t|^2 + 512 > 0 (split-independent).
// key = (bits(score)&~0x7FF) | local_ctx_idx (10 bits used).
__global__ __launch_bounds__(256) void k_dist_mfma(const __bf16* __restrict__ XcB,
                                                   const __bf16* __restrict__ XtB,
                                                   const float* __restrict__ nrm,
                                                   unsigned* __restrict__ cand) {
  __shared__ __bf16 lds[2][32 * CH];   // 2 x 16 KB ctx tiles, fragment-linear order
  const int lid = blockIdx.x;
  const int xk = lid & 7;
  const int b = xk >> 1, jh = xk & 1;
  const int jw = (lid >> 3) & 15, split = lid >> 7;
  const int t = threadIdx.x, w = t >> 6, lane = t & 63;
  const int l31 = lane & 31, lh = lane >> 5;
  const int tgt0 = (jh * 16 + jw) * 128 + w * 32;
  const int cbase = split * CTX_PER;
  const float* nrmt = nrm + (long)b * NCTX + cbase;   // -0.5*|c|^2

  const __bf16* tp = XtB + ((long)b * NT + tgt0 + l31) * CH + lh * 8;
  bf16x8 bfrag[16];
#pragma unroll
  for (int s = 0; s < 16; ++s) bfrag[s] = *(const bf16x8*)(tp + s * 16);

  unsigned kd[CSEL];
#pragma unroll
  for (int q = 0; q < CSEL; ++q) kd[q] = 0xFFFFFFFFu;

  const __bf16* cp = XcB + ((long)b * NCTX + cbase + l31) * CH;

  auto STAGE = [&](int buf, int jt) {
#pragma unroll
    for (int r = 0; r < 4; ++r) {
      int c = r * 4 + w;
      const __bf16* src = cp + (long)jt * 32 * CH + (c * 2 + lh) * 8;
      __bf16* dst = &lds[buf][c * 512];
      __builtin_amdgcn_global_load_lds((const __attribute__((address_space(1))) void*)src,
                                       (__attribute__((address_space(3))) void*)dst,
                                       16, 0, 0);
    }
  };

  STAGE(0, 0);
  __syncthreads();

  int cur = 0;
  for (int jt = 0; jt < NTILE; ++jt) {
    if (jt + 1 < NTILE) STAGE(cur ^ 1, jt + 1);

    const int ct0 = jt * 32;
    f32x16 acc;
#pragma unroll
    for (int g = 0; g < 4; ++g) {
      float4 nv = *(const float4*)&nrmt[ct0 + 8 * g + 4 * lh];
      acc[4 * g + 0] = nv.x; acc[4 * g + 1] = nv.y;
      acc[4 * g + 2] = nv.z; acc[4 * g + 3] = nv.w;
    }
#pragma unroll
    for (int s = 0; s < 16; ++s) {
      bf16x8 a = *(const bf16x8*)(&lds[cur][s * 512 + lane * 8]);
      acc = __builtin_amdgcn_mfma_f32_32x32x16_bf16(a, bfrag[s], acc, 0, 0, 0);
    }

#pragma unroll
    for (int reg = 0; reg < 16; ++reg) {
      const int row = (reg & 3) + 8 * (reg >> 2) + lh * 4;
      float sc = fmaf(acc[reg], -2.0f, 512.0f);
      unsigned key = (__float_as_uint(sc) & 0xFFFFF800u) | (unsigned)ct0 | (unsigned)row;
#pragma unroll
      for (int q = 0; q < CSEL; ++q) {   // branchless sorted-ascending bubble insert
        unsigned lo = min(key, kd[q]);
        key = max(key, kd[q]);
        kd[q] = lo;
      }
    }
    __syncthreads();
    cur ^= 1;
  }

  unsigned oth[CSEL];
#pragma unroll
  for (int q = 0; q < CSEL; ++q) oth[q] = (unsigned)__shfl_xor((int)kd[q], 32, 64);
  if (lh == 0) {
    long ob = (((long)b * NT + tgt0 + l31) * DNSPLIT + split) * CSEL;
#pragma unroll
    for (int q = 0; q < CSEL; ++q)
      cand[ob + q] = min(kd[q], oth[CSEL - 1 - q]);   // raw key
  }
}

// ---------------- rescore: coarse top-RESC of 80 keys, fp64 exact, rank-8 + counts ----------------
__global__ __launch_bounds__(64) void k_rescore(const float* __restrict__ XtT,
                                                const float* __restrict__ XcT,
                                                const unsigned* __restrict__ cand,
                                                int* __restrict__ knn,
                                                unsigned* __restrict__ counts) {
  const int n = blockIdx.x, b = blockIdx.y, lane = threadIdx.x;
  const int grp = lane >> 4, gl = lane & 15;
  __shared__ unsigned sk[NKEY];
  __shared__ int cidx[RESC];
  __shared__ double sd[RESC];
  __shared__ int sj[RESC];
  const unsigned* kp = cand + ((long)b * NT + n) * NKEY;
  unsigned k0 = kp[lane];
  unsigned k1 = (lane < NKEY - 64) ? kp[64 + lane] : 0xFFFFFFFFu;
  sk[lane] = k0;
  if (lane < NKEY - 64) sk[64 + lane] = k1;
  __syncthreads();
  int r0 = 0, r1 = 0;
  for (int i = 0; i < NKEY; ++i) {
    unsigned s = sk[i];
    r0 += (s < k0 || (s == k0 && i < lane)) ? 1 : 0;
    r1 += (s < k1 || (s == k1 && i < 64 + lane)) ? 1 : 0;
  }
  if (r0 < RESC) cidx[r0] = (lane / CSEL) * CTX_PER + (int)(k0 & 0x7FFu);
  if (lane < NKEY - 64 && r1 < RESC)
    cidx[r1] = ((64 + lane) / CSEL) * CTX_PER + (int)(k1 & 0x7FFu);
  __syncthreads();

  const float* xt = XtT + ((long)b * NT + n) * CH + gl * 16;
  double xa[16];
#pragma unroll
  for (int r = 0; r < 4; ++r) {
    float4 v = *(const float4*)(xt + r * 4);
    xa[4 * r + 0] = (double)v.x; xa[4 * r + 1] = (double)v.y;
    xa[4 * r + 2] = (double)v.z; xa[4 * r + 3] = (double)v.w;
  }
#pragma unroll
  for (int q0 = 0; q0 < RESC; q0 += 4) {
    int q = q0 + grp;
    int j = cidx[q];
    const float* xc = XcT + ((long)b * NCTX + j) * CH + gl * 16;
    double acc = 0.0;
#pragma unroll
    for (int r = 0; r < 4; ++r) {
      float4 v = *(const float4*)(xc + r * 4);
      double d0 = xa[4 * r + 0] - (double)v.x; acc = fma(d0, d0, acc);
      double d1 = xa[4 * r + 1] - (double)v.y; acc = fma(d1, d1, acc);
      double d2 = xa[4 * r + 2] - (double)v.z; acc = fma(d2, d2, acc);
      double d3 = xa[4 * r + 3] - (double)v.w; acc = fma(d3, d3, acc);
    }
#pragma unroll
    for (int off = 8; off > 0; off >>= 1) acc += __shfl_xor(acc, off, 64);
    if (gl == 0) { sd[q] = acc; sj[q] = j; }
  }
  __syncthreads();
  double dq = (lane < RESC) ? sd[lane] : DBL_MAX;
  int    jq = (lane < RESC) ? sj[lane] : 0x7fffffff;
  int rank = 0;
#pragma unroll
  for (int i = 0; i < RESC; ++i) {
    double di = sd[i]; int ji = sj[i];
    rank += (di < dq || (di == dq && ji < jq)) ? 1 : 0;
  }
  if (lane < RESC && rank < KI) {
    knn[((long)b * NT + n) * KI + rank] = jq;
    atomicAdd(&counts[(long)b * NCTX + jq], 1u);
  }
}

// ---------------- CSR build: per-batch exclusive scan of counts -> offs + cursor ----------------
__global__ __launch_bounds__(256) void k_scan(const unsigned* __restrict__ counts,
                                              int* __restrict__ offs,
                                              int* __restrict__ cursor) {
  const int b = blockIdx.x, t = threadIdx.x;
  __shared__ int ps[256];
  const unsigned* c = counts + (long)b * NCTX;
  int loc[32]; int s = 0;
#pragma unroll
  for (int i = 0; i < 32; ++i) { loc[i] = (int)c[t * 32 + i]; s += loc[i]; }
  ps[t] = s;
  __syncthreads();
  for (int off = 1; off < 256; off <<= 1) {
    int v = (t >= off) ? ps[t - off] : 0;
    __syncthreads();
    ps[t] += v;
    __syncthreads();
  }
  int base = t ? ps[t - 1] : 0;
  int* ob = offs + (long)b * NCTX;
  int* cb = cursor + (long)b * NCTX;
#pragma unroll
  for (int i = 0; i < 32; ++i) { ob[t * 32 + i] = base; cb[t * 32 + i] = base; base += loc[i]; }
}

// ---------------- CSR fill: edge list (ctx -> incident targets) ----------------
__global__ __launch_bounds__(256) void k_fill(const int* __restrict__ knn,
                                              int* __restrict__ cursor,
                                              int* __restrict__ elist) {
  const int idx = blockIdx.x * 256 + threadIdx.x;   // over BATCH*NT
  const int b = idx >> 12, n = idx & (NT - 1);
  const int* kn = knn + (long)idx * KI;
#pragma unroll
  for (int q = 0; q < KI; ++q) {
    int j = kn[q];
    int pos = atomicAdd(&cursor[(long)b * NCTX + j], 1);
    elist[(long)b * NT * KI + pos] = n;
  }
}

// ---------------- bf16 MFMA GEMM + bias, 3-term hi/lo split (node2edge linear) ----------------
__global__ __launch_bounds__(256) void k_gemm_mfma(const unsigned short* __restrict__ Ah,
                                                   const unsigned short* __restrict__ Al,
                                                   const unsigned short* __restrict__ WTh,
                                                   const unsigned short* __restrict__ WTl,
                                                   const float* __restrict__ bias,
                                                   float* __restrict__ out, int M) {
  __shared__ __bf16 ldsH[32 * CH];
  __shared__ __bf16 ldsL[32 * CH];
  const int b = blockIdx.y;
  const int m0 = blockIdx.x * 32;
  const int t = threadIdx.x, w = t >> 6, lane = t & 63;
  const int l31 = lane & 31, lh = lane >> 5;
  const long abase = (long)b * M * CH;
  const unsigned short* pH = Ah + abase + (long)(m0 + l31) * CH;
  const unsigned short* pL = Al + abase + (long)(m0 + l31) * CH;
#pragma unroll
  for (int r = 0; r < 4; ++r) {
    int c = r * 4 + w;
    __builtin_amdgcn_global_load_lds(
        (const __attribute__((address_space(1))) void*)(pH + (c * 2 + lh) * 8),
        (__attribute__((address_space(3))) void*)&ldsH[c * 512], 16, 0, 0);
    __builtin_amdgcn_global_load_lds(
        (const __attribute__((address_space(1))) void*)(pL + (c * 2 + lh) * 8),
        (__attribute__((address_space(3))) void*)&ldsL[c * 512], 16, 0, 0);
  }
  __syncthreads();

  const int n0 = w * 64;
  f32x16 acc0, acc1;
#pragma unroll
  for (int i = 0; i < 16; ++i) { acc0[i] = 0.f; acc1[i] = 0.f; }
#pragma unroll
  for (int s = 0; s < 16; ++s) {
    bf16x8 ah = *(const bf16x8*)&ldsH[s * 512 + lane * 8];
    bf16x8 al = *(const bf16x8*)&ldsL[s * 512 + lane * 8];
    const int koff = lh * 8 + s * 16;
    bf16x8 bh0 = *(const bf16x8*)&WTh[(n0 + l31) * CH + koff];
    bf16x8 bl0 = *(const bf16x8*)&WTl[(n0 + l31) * CH + koff];
    bf16x8 bh1 = *(const bf16x8*)&WTh[(n0 + 32 + l31) * CH + koff];
    bf16x8 bl1 = *(const bf16x8*)&WTl[(n0 + 32 + l31) * CH + koff];
    acc0 = __builtin_amdgcn_mfma_f32_32x32x16_bf16(ah, bh0, acc0, 0, 0, 0);
    acc1 = __builtin_amdgcn_mfma_f32_32x32x16_bf16(ah, bh1, acc1, 0, 0, 0);
    acc0 = __builtin_amdgcn_mfma_f32_32x32x16_bf16(ah, bl0, acc0, 0, 0, 0);
    acc1 = __builtin_amdgcn_mfma_f32_32x32x16_bf16(ah, bl1, acc1, 0, 0, 0);
    acc0 = __builtin_amdgcn_mfma_f32_32x32x16_bf16(al, bh0, acc0, 0, 0, 0);
    acc1 = __builtin_amdgcn_mfma_f32_32x32x16_bf16(al, bh1, acc1, 0, 0, 0);
  }
  float* ob = out + abase;
  float bi0 = bias[n0 + l31], bi1 = bias[n0 + 32 + l31];
#pragma unroll
  for (int reg = 0; reg < 16; ++reg) {
    int row = (reg & 3) + 8 * (reg >> 2) + 4 * lh;
    ob[(long)(m0 + row) * CH + n0 + l31]      = acc0[reg] + bi0;
    ob[(long)(m0 + row) * CH + n0 + 32 + l31] = acc1[reg] + bi1;
  }
}

// ---------------- gather-mean: X_edge = (Xn_t + sum_k Xn_c[knn]) / 9 -> bf16 hi/lo ----------------
__global__ __launch_bounds__(256) void k_gather(const float* __restrict__ Xn_t,
                                                const float* __restrict__ Xn_c,
                                                const int* __restrict__ knn,
                                                unsigned short* __restrict__ XeH,
                                                unsigned short* __restrict__ XeL) {
  const int n = blockIdx.x, b = blockIdx.y, c = threadIdx.x;
  const int* kn = knn + ((long)b * NT + n) * KI;
  int j[KI];
#pragma unroll
  for (int q = 0; q < KI; ++q) j[q] = kn[q];
  float acc = Xn_t[((long)b * NT + n) * CH + c];
#pragma unroll
  for (int q = 0; q < KI; ++q) acc += Xn_c[((long)b * NCTX + j[q]) * CH + c];
  float xe = acc / 9.0f;
  long o = ((long)b * NT + n) * CH + c;
  unsigned short h = bf16_rne(xe);
  XeH[o] = h;
  float hf = __uint_as_float((unsigned)h << 16);
  XeL[o] = bf16_rne(xe - hf);
}

// ---------------- fused edge2node GEMM + dual output (out_t direct + X_et rows) ----------------
// MFMA with a = WT2 rows (out-channels), b = Xe fragments -> C[ch][node]; epilogue adds bias,
// stores out_t image-layout coalesced, and LDS-pad transposes to R[node][ch] for ctxgather.
__global__ __launch_bounds__(256) void k_g2f(const unsigned short* __restrict__ XeH_g,
                                             const unsigned short* __restrict__ XeL_g,
                                             const unsigned short* __restrict__ WTh,
                                             const unsigned short* __restrict__ WTl,
                                             const float* __restrict__ bias,
                                             float* __restrict__ out_t,
                                             float* __restrict__ R) {
  __shared__ char smem[34816];   // phase A/B: 2x16KB Xe staging; phase C: float S[256][33]
  __bf16* ldsH = (__bf16*)smem;
  __bf16* ldsL = (__bf16*)(smem + 16384);
  const int b = blockIdx.y;
  const int m0 = blockIdx.x * 32;
  const int t = threadIdx.x, w = t >> 6, lane = t & 63;
  const int l31 = lane & 31, lh = lane >> 5;
  const long abase = (long)b * NT * CH;
  const unsigned short* pH = XeH_g + abase + (long)(m0 + l31) * CH;
  const unsigned short* pL = XeL_g + abase + (long)(m0 + l31) * CH;
#pragma unroll
  for (int r = 0; r < 4; ++r) {
    int c = r * 4 + w;
    __builtin_amdgcn_global_load_lds(
        (const __attribute__((address_space(1))) void*)(pH + (c * 2 + lh) * 8),
        (__attribute__((address_space(3))) void*)&ldsH[c * 512], 16, 0, 0);
    __builtin_amdgcn_global_load_lds(
        (const __attribute__((address_space(1))) void*)(pL + (c * 2 + lh) * 8),
        (__attribute__((address_space(3))) void*)&ldsL[c * 512], 16, 0, 0);
  }
  __syncthreads();

  const unsigned short* wh0 = WTh + (long)(w * 64 + l31) * CH;
  const unsigned short* wl0 = WTl + (long)(w * 64 + l31) * CH;
  f32x16 acc0, acc1;
#pragma unroll
  for (int i = 0; i < 16; ++i) { acc0[i] = 0.f; acc1[i] = 0.f; }
#pragma unroll
  for (int s = 0; s < 16; ++s) {
    const int koff = lh * 8 + s * 16;
    bf16x8 beh = *(const bf16x8*)&ldsH[s * 512 + lane * 8];
    bf16x8 bel = *(const bf16x8*)&ldsL[s * 512 + lane * 8];
    bf16x8 ah0 = *(const bf16x8*)(const __bf16*)(wh0 + koff);
    bf16x8 al0 = *(const bf16x8*)(const __bf16*)(wl0 + koff);
    bf16x8 ah1 = *(const bf16x8*)(const __bf16*)(wh0 + 32 * CH + koff);
    bf16x8 al1 = *(const bf16x8*)(const __bf16*)(wl0 + 32 * CH + koff);
    acc0 = __builtin_amdgcn_mfma_f32_32x32x16_bf16(ah0, beh, acc0, 0, 0, 0);
    acc1 = __builtin_amdgcn_mfma_f32_32x32x16_bf16(ah1, beh, acc1, 0, 0, 0);
    acc0 = __builtin_amdgcn_mfma_f32_32x32x16_bf16(al0, beh, acc0, 0, 0, 0);
    acc1 = __builtin_amdgcn_mfma_f32_32x32x16_bf16(al1, beh, acc1, 0, 0, 0);
    acc0 = __builtin_amdgcn_mfma_f32_32x32x16_bf16(ah0, bel, acc0, 0, 0, 0);
    acc1 = __builtin_amdgcn_mfma_f32_32x32x16_bf16(ah1, bel, acc1, 0, 0, 0);
  }
  __syncthreads();   // staging reads done; smem reusable

  float* S = (float*)smem;               // [256][33]
  float* ot = out_t + (long)b * CH * NT + m0;
#pragma unroll
  for (int reg = 0; reg < 16; ++reg) {
    const int row = (reg & 3) + 8 * (reg >> 2) + 4 * lh;
    const int ch0 = w * 64 + row, ch1 = ch0 + 32;
    float v0 = acc0[reg] + bias[ch0];
    float v1 = acc1[reg] + bias[ch1];
    S[ch0 * 33 + l31] = v0;
    S[ch1 * 33 + l31] = v1;
    ot[(long)ch0 * NT + l31] = v0;
    ot[(long)ch1 * NT + l31] = v1;
  }
  __syncthreads();
  const int n = t & 31, cg = t >> 5;
  float* rrow = R + ((long)b * NT + m0 + n) * CH;
#pragma unroll
  for (int kk = 0; kk < 8; ++kk) {
    const int c = cg * 32 + kk * 4;
    float4 v;
    v.x = S[(c + 0) * 33 + n];
    v.y = S[(c + 1) * 33 + n];
    v.z = S[(c + 2) * 33 + n];
    v.w = S[(c + 3) * 33 + n];
    *(float4*)(rrow + c) = v;
  }
}

// ---------------- CSR context aggregation: out_c = mean of incident X_et rows, image layout ----------------
__global__ __launch_bounds__(256) void k_ctxgather(const float* __restrict__ Xet,
                                                   const int* __restrict__ offs,
                                                   const unsigned* __restrict__ counts,
                                                   const int* __restrict__ elist,
                                                   float* __restrict__ out1,
                                                   float* __restrict__ out2) {
  __shared__ float S[32][257];
  const int b = blockIdx.y, j0 = blockIdx.x * 32;
  const int t = threadIdx.x;
  const int nl = t >> 3, sub = t & 7;          // node-local, channel-strip of 32
  const int j = j0 + nl;
  const int off = offs[(long)b * NCTX + j];
  const int deg = (int)counts[(long)b * NCTX + j];
  const int* el = elist + (long)b * NT * KI;
  const float* xb = Xet + (long)b * NT * CH + sub * 32;
  float acc[32];
#pragma unroll
  for (int i = 0; i < 32; ++i) acc[i] = 0.f;
  for (int e = 0; e < deg; ++e) {
    const float* row = xb + (long)el[off + e] * CH;
#pragma unroll
    for (int r = 0; r < 8; ++r) {
      float4 v = *(const float4*)(row + r * 4);
      acc[r * 4 + 0] += v.x; acc[r * 4 + 1] += v.y;
      acc[r * 4 + 2] += v.z; acc[r * 4 + 3] += v.w;
    }
  }
  const float inv = 1.0f / fmaxf((float)deg, 1.0f);
#pragma unroll
  for (int i = 0; i < 32; ++i) S[nl][sub * 32 + i] = acc[i] * inv;
  __syncthreads();
  float* outp = (j0 < NT) ? (out1 + (long)b * CH * NT + j0)
                          : (out2 + (long)b * CH * NT + (j0 - NT));
  const int tx = t & 31, ty = t >> 5;
#pragma unroll
  for (int c = ty; c < CH; c += 8)
    outp[(long)c * NT + tx] = S[tx][c];
}

extern "C" void kernel_launch(void* const* d_in, const int* in_sizes, int n_in,
                              void* d_out, int out_size, void* d_ws, size_t ws_size,
                              hipStream_t stream) {
  const float* Xt  = (const float*)d_in[0];
  const float* Xc1 = (const float*)d_in[1];
  const float* Xc2 = (const float*)d_in[2];
  const float* W1  = (const float*)d_in[3];
  const float* b1  = (const float*)d_in[4];
  const float* W2  = (const float*)d_in[5];
  const float* b2  = (const float*)d_in[6];
  float* out = (float*)d_out;

  // ws layout (~69.1 MB)
  float* P = (float*)d_ws;                               // 33.55 MB  XcT -> Xn_c
  float* Q = P + (long)BATCH * NCTX * CH;                // 16.78 MB  XtT -> XeH/XeL
  float* R = Q + (long)BATCH * NT * CH;                  // 16.78 MB  cand -> Xn_t -> X_et
  float* nrm = R + (long)BATCH * NT * CH;                // 128 KB
  unsigned* counts = (unsigned*)(nrm + (long)BATCH * NCTX);  // 128 KB
  int* knn = (int*)(counts + (long)BATCH * NCTX);        // 512 KB
  unsigned short* WT1h = (unsigned short*)(knn + (long)BATCH * NT * KI);
  unsigned short* WT1l = WT1h + CH * CH;
  unsigned short* WT2h = WT1l + CH * CH;
  unsigned short* WT2l = WT2h + CH * CH;                 // 4 x 128 KB
  int* offs   = (int*)(WT2l + CH * CH);                  // 128 KB
  int* cursor = offs + (long)BATCH * NCTX;               // 128 KB
  int* elist  = cursor + (long)BATCH * NCTX;             // 512 KB

  unsigned* cand = (unsigned*)R;   // 5.24 MB, dead before gemm1 writes Xn_t to R

  unsigned short* XcBh = (unsigned short*)d_out;
  unsigned short* XtBh = XcBh + (long)BATCH * NCTX * CH;
  unsigned short* XcBl = XtBh + (long)BATCH * NT * CH;
  unsigned short* XtBl = XcBl + (long)BATCH * NCTX * CH;

  float* Xn_c = P;
  float* Xn_t = R;
  unsigned short* XeH = (unsigned short*)Q;   // after rescore, Q (XtT) is dead
  unsigned short* XeL = XeH + (long)BATCH * NT * CH;

  float* out_t  = out;             // overwrites dead XcBh region (after gemm1 reads)
  float* out_c1 = out + (long)BATCH * CH * NT;
  float* out_c2 = out + 2L * BATCH * CH * NT;

  dim3 tb(32, 8);

  hipMemsetAsync(nrm, 0, (size_t)BATCH * NCTX * 8, stream);   // nrm + counts

  k_wtrans<<<dim3(8, 8, 2), tb, 0, stream>>>(W1, W2, WT1h, WT1l, WT2h, WT2l);

  k_transpose2<<<dim3(NT / 32, CH / 64, 12), tb, 0, stream>>>(
      Xt, Xc1, Xc2, Q, P, XtBh, XtBl, XcBh, XcBl, nrm);

  k_dist_mfma<<<dim3(8 * 16 * DNSPLIT), 256, 0, stream>>>(
      (const __bf16*)XcBh, (const __bf16*)XtBh, nrm, cand);

  k_rescore<<<dim3(NT, BATCH), 64, 0, stream>>>(Q, P, cand, knn, counts);

  // CSR build (counts final after rescore)
  k_scan<<<dim3(BATCH), 256, 0, stream>>>(counts, offs, cursor);
  k_fill<<<dim3(BATCH * NT / 256), 256, 0, stream>>>(knn, cursor, elist);

  // node2edge linear (bf16 MFMA, 3-term): Xn_t -> R, Xn_c -> P
  k_gemm_mfma<<<dim3(NT / 32, BATCH), 256, 0, stream>>>(XtBh, XtBl, WT1h, WT1l, b1, Xn_t, NT);
  k_gemm_mfma<<<dim3(NCTX / 32, BATCH), 256, 0, stream>>>(XcBh, XcBl, WT1h, WT1l, b1, Xn_c, NCTX);

  // edge mean-pool -> Q as bf16 hi/lo
  k_gather<<<dim3(NT, BATCH), 256, 0, stream>>>(Xn_t, Xn_c, knn, XeH, XeL);

  // fused edge2node + out_t + X_et rows
  k_g2f<<<dim3(NT / 32, BATCH), 256, 0, stream>>>(XeH, XeL, WT2h, WT2l, b2, out_t, R);

  // CSR context aggregation -> out_c (replaces memset + scatter + fin_c)
  k_ctxgather<<<dim3(NCTX / 32, BATCH), 256, 0, stream>>>(R, offs, counts, elist, out_c1, out_c2);
}

// Round 11
// 437.133 us; speedup vs baseline: 1.1078x; 1.0695x over previous
//
#include <hip/hip_runtime.h>
#include <math.h>
#include <float.h>

#define BATCH 4
#define CH    256
#define NT    4096
#define NCTX  8192
#define KI    8

// coarse-selection geometry
#define CSEL    10                 // per-split top-C after lane-half merge (>=8+2 slack => safe)
#define DNSPLIT 8                  // ctx splits
#define CTX_PER (NCTX / DNSPLIT)   // 1024
#define NTILE   (CTX_PER / 32)     // 32 tiles of 32 ctx
#define NKEY    (DNSPLIT * CSEL)   // 80 packed keys per target
#define RESC    12                 // keys kept for exact fp64 rescore

typedef __attribute__((ext_vector_type(8)))  __bf16 bf16x8;
typedef __attribute__((ext_vector_type(16))) float  f32x16;

__device__ __forceinline__ unsigned short bf16_rne(float v) {
  unsigned u = __float_as_uint(v);
  return (unsigned short)((u + 0x7fffu + ((u >> 16) & 1u)) >> 16);
}

// ---------------- merged transpose: [CH][NT] -> [NT][CH] fp32 + bf16 hi/lo, + ctx norms ----------------
__global__ __launch_bounds__(256) void k_transpose2(const float* __restrict__ Xt,
                                                    const float* __restrict__ Xc1,
                                                    const float* __restrict__ Xc2,
                                                    float* __restrict__ Q,
                                                    float* __restrict__ P,
                                                    unsigned short* __restrict__ XtBh,
                                                    unsigned short* __restrict__ XtBl,
                                                    unsigned short* __restrict__ XcBh,
                                                    unsigned short* __restrict__ XcBl,
                                                    float* __restrict__ nrm) {
  __shared__ float tile[64][33];
  __shared__ float ps[8][32];
  const int which = blockIdx.z >> 2, b = blockIdx.z & 3;
  const float* src;
  float* dF; unsigned short *dH, *dL; float* nrmp = nullptr;
  if (which == 0) {
    src = Xt + (long)b * CH * NT;
    dF = Q + (long)b * NT * CH;
    dH = XtBh + (long)b * NT * CH;  dL = XtBl + (long)b * NT * CH;
  } else if (which == 1) {
    src = Xc1 + (long)b * CH * NT;
    dF = P + (long)b * NCTX * CH;
    dH = XcBh + (long)b * NCTX * CH;  dL = XcBl + (long)b * NCTX * CH;
    nrmp = nrm + (long)b * NCTX;
  } else {
    src = Xc2 + (long)b * CH * NT;
    dF = P + ((long)b * NCTX + NT) * CH;
    dH = XcBh + ((long)b * NCTX + NT) * CH;  dL = XcBl + ((long)b * NCTX + NT) * CH;
    nrmp = nrm + (long)b * NCTX + NT;
  }
  const int m0 = blockIdx.x * 32, c0 = blockIdx.y * 64;
  const int tx = threadIdx.x, ty = threadIdx.y;
  float part = 0.f;
#pragma unroll
  for (int i = ty; i < 64; i += 8) {
    float v = src[(long)(c0 + i) * NT + (m0 + tx)];
    tile[i][tx] = v;
    part = fmaf(v, v, part);
  }
  if (which) ps[ty][tx] = part;
  __syncthreads();
#pragma unroll
  for (int i = ty; i < 32; i += 8) {
    float v0 = tile[2 * tx][i];
    float v1 = tile[2 * tx + 1][i];
    long o = (long)(m0 + i) * CH + (c0 + 2 * tx);
    float2 f2; f2.x = v0; f2.y = v1;
    *(float2*)&dF[o] = f2;
    unsigned short h0 = bf16_rne(v0), h1 = bf16_rne(v1);
    ushort2 h2; h2.x = h0; h2.y = h1;
    *(ushort2*)&dH[o] = h2;
    float hf0 = __uint_as_float((unsigned)h0 << 16);
    float hf1 = __uint_as_float((unsigned)h1 << 16);
    ushort2 l2; l2.x = bf16_rne(v0 - hf0); l2.y = bf16_rne(v1 - hf1);
    *(ushort2*)&dL[o] = l2;
  }
  if (which && ty == 0) {
    float s = 0.f;
#pragma unroll
    for (int j = 0; j < 8; ++j) s += ps[j][tx];
    atomicAdd(&nrmp[m0 + tx], -0.5f * s);
  }
}

// ---------------- W transpose: fp32 [CH(k)][CH(n)] -> bf16 hi/lo WT[n][k]; z = which W ----------------
__global__ __launch_bounds__(256) void k_wtrans(const float* __restrict__ W1,
                                                const float* __restrict__ W2,
                                                unsigned short* __restrict__ WT1h,
                                                unsigned short* __restrict__ WT1l,
                                                unsigned short* __restrict__ WT2h,
                                                unsigned short* __restrict__ WT2l) {
  __shared__ float tile[32][33];
  const float* W = blockIdx.z ? W2 : W1;
  unsigned short* WTh = blockIdx.z ? WT2h : WT1h;
  unsigned short* WTl = blockIdx.z ? WT2l : WT1l;
  const int n0 = blockIdx.x * 32, k0 = blockIdx.y * 32;
  const int tx = threadIdx.x, ty = threadIdx.y;
#pragma unroll
  for (int i = ty; i < 32; i += 8)
    tile[i][tx] = W[(k0 + i) * CH + (n0 + tx)];
  __syncthreads();
#pragma unroll
  for (int i = ty; i < 32; i += 8) {
    float v = tile[tx][i];
    int o = (n0 + i) * CH + (k0 + tx);
    unsigned short h = bf16_rne(v);
    WTh[o] = h;
    float hf = __uint_as_float((unsigned)h << 16);
    WTl[o] = bf16_rne(v - hf);
  }
}

// ---------------- MFMA coarse scorer + per-lane top-CSEL (unguarded bubble), XCD-swizzled ----------------
// lid = (b*2+jh) + 8*(jw + 16*split); XCD(lid)=lid%8 owns one (batch, j-half); split slowest.
// C/D layout: col = lane&31 (target), row = (reg&3) + 8*(reg>>2) + 4*(lane>>5) (ctx).
// acc init with -0.5*|c|^2 so score = -2*acc + 512 = d^2 - |t|^2 + 512 > 0 (split-independent).
// key = (bits(score)&~0x7FF) | local_ctx_idx (10 bits used).
__global__ __launch_bounds__(256) void k_dist_mfma(const __bf16* __restrict__ XcB,
                                                   const __bf16* __restrict__ XtB,
                                                   const float* __restrict__ nrm,
                                                   unsigned* __restrict__ cand) {
  __shared__ __bf16 lds[2][32 * CH];   // 2 x 16 KB ctx tiles, fragment-linear order
  const int lid = blockIdx.x;
  const int xk = lid & 7;
  const int b = xk >> 1, jh = xk & 1;
  const int jw = (lid >> 3) & 15, split = lid >> 7;
  const int t = threadIdx.x, w = t >> 6, lane = t & 63;
  const int l31 = lane & 31, lh = lane >> 5;
  const int tgt0 = (jh * 16 + jw) * 128 + w * 32;
  const int cbase = split * CTX_PER;
  const float* nrmt = nrm + (long)b * NCTX + cbase;   // -0.5*|c|^2

  const __bf16* tp = XtB + ((long)b * NT + tgt0 + l31) * CH + lh * 8;
  bf16x8 bfrag[16];
#pragma unroll
  for (int s = 0; s < 16; ++s) bfrag[s] = *(const bf16x8*)(tp + s * 16);

  unsigned kd[CSEL];
#pragma unroll
  for (int q = 0; q < CSEL; ++q) kd[q] = 0xFFFFFFFFu;

  const __bf16* cp = XcB + ((long)b * NCTX + cbase + l31) * CH;

  auto STAGE = [&](int buf, int jt) {
#pragma unroll
    for (int r = 0; r < 4; ++r) {
      int c = r * 4 + w;
      const __bf16* src = cp + (long)jt * 32 * CH + (c * 2 + lh) * 8;
      __bf16* dst = &lds[buf][c * 512];
      __builtin_amdgcn_global_load_lds((const __attribute__((address_space(1))) void*)src,
                                       (__attribute__((address_space(3))) void*)dst,
                                       16, 0, 0);
    }
  };

  STAGE(0, 0);
  __syncthreads();

  int cur = 0;
  for (int jt = 0; jt < NTILE; ++jt) {
    if (jt + 1 < NTILE) STAGE(cur ^ 1, jt + 1);

    const int ct0 = jt * 32;
    f32x16 acc;
#pragma unroll
    for (int g = 0; g < 4; ++g) {
      float4 nv = *(const float4*)&nrmt[ct0 + 8 * g + 4 * lh];
      acc[4 * g + 0] = nv.x; acc[4 * g + 1] = nv.y;
      acc[4 * g + 2] = nv.z; acc[4 * g + 3] = nv.w;
    }
#pragma unroll
    for (int s = 0; s < 16; ++s) {
      bf16x8 a = *(const bf16x8*)(&lds[cur][s * 512 + lane * 8]);
      acc = __builtin_amdgcn_mfma_f32_32x32x16_bf16(a, bfrag[s], acc, 0, 0, 0);
    }

#pragma unroll
    for (int reg = 0; reg < 16; ++reg) {
      const int row = (reg & 3) + 8 * (reg >> 2) + lh * 4;
      float sc = fmaf(acc[reg], -2.0f, 512.0f);
      unsigned key = (__float_as_uint(sc) & 0xFFFFF800u) | (unsigned)ct0 | (unsigned)row;
#pragma unroll
      for (int q = 0; q < CSEL; ++q) {   // branchless sorted-ascending bubble insert
        unsigned lo = min(key, kd[q]);
        key = max(key, kd[q]);
        kd[q] = lo;
      }
    }
    __syncthreads();
    cur ^= 1;
  }

  unsigned oth[CSEL];
#pragma unroll
  for (int q = 0; q < CSEL; ++q) oth[q] = (unsigned)__shfl_xor((int)kd[q], 32, 64);
  if (lh == 0) {
    long ob = (((long)b * NT + tgt0 + l31) * DNSPLIT + split) * CSEL;
#pragma unroll
    for (int q = 0; q < CSEL; ++q)
      cand[ob + q] = min(kd[q], oth[CSEL - 1 - q]);   // raw key
  }
}

// ---------------- rescore: coarse top-RESC of 80 keys, fp64 exact, rank-8 + counts ----------------
__global__ __launch_bounds__(64) void k_rescore(const float* __restrict__ XtT,
                                                const float* __restrict__ XcT,
                                                const unsigned* __restrict__ cand,
                                                int* __restrict__ knn,
                                                unsigned* __restrict__ counts) {
  const int n = blockIdx.x, b = blockIdx.y, lane = threadIdx.x;
  const int grp = lane >> 4, gl = lane & 15;
  __shared__ unsigned sk[NKEY];
  __shared__ int cidx[RESC];
  __shared__ double sd[RESC];
  __shared__ int sj[RESC];
  const unsigned* kp = cand + ((long)b * NT + n) * NKEY;
  unsigned k0 = kp[lane];
  unsigned k1 = (lane < NKEY - 64) ? kp[64 + lane] : 0xFFFFFFFFu;
  sk[lane] = k0;
  if (lane < NKEY - 64) sk[64 + lane] = k1;
  __syncthreads();
  int r0 = 0, r1 = 0;
  for (int i = 0; i < NKEY; ++i) {
    unsigned s = sk[i];
    r0 += (s < k0 || (s == k0 && i < lane)) ? 1 : 0;
    r1 += (s < k1 || (s == k1 && i < 64 + lane)) ? 1 : 0;
  }
  if (r0 < RESC) cidx[r0] = (lane / CSEL) * CTX_PER + (int)(k0 & 0x7FFu);
  if (lane < NKEY - 64 && r1 < RESC)
    cidx[r1] = ((64 + lane) / CSEL) * CTX_PER + (int)(k1 & 0x7FFu);
  __syncthreads();

  const float* xt = XtT + ((long)b * NT + n) * CH + gl * 16;
  double xa[16];
#pragma unroll
  for (int r = 0; r < 4; ++r) {
    float4 v = *(const float4*)(xt + r * 4);
    xa[4 * r + 0] = (double)v.x; xa[4 * r + 1] = (double)v.y;
    xa[4 * r + 2] = (double)v.z; xa[4 * r + 3] = (double)v.w;
  }
#pragma unroll
  for (int q0 = 0; q0 < RESC; q0 += 4) {
    int q = q0 + grp;
    int j = cidx[q];
    const float* xc = XcT + ((long)b * NCTX + j) * CH + gl * 16;
    double acc = 0.0;
#pragma unroll
    for (int r = 0; r < 4; ++r) {
      float4 v = *(const float4*)(xc + r * 4);
      double d0 = xa[4 * r + 0] - (double)v.x; acc = fma(d0, d0, acc);
      double d1 = xa[4 * r + 1] - (double)v.y; acc = fma(d1, d1, acc);
      double d2 = xa[4 * r + 2] - (double)v.z; acc = fma(d2, d2, acc);
      double d3 = xa[4 * r + 3] - (double)v.w; acc = fma(d3, d3, acc);
    }
#pragma unroll
    for (int off = 8; off > 0; off >>= 1) acc += __shfl_xor(acc, off, 64);
    if (gl == 0) { sd[q] = acc; sj[q] = j; }
  }
  __syncthreads();
  double dq = (lane < RESC) ? sd[lane] : DBL_MAX;
  int    jq = (lane < RESC) ? sj[lane] : 0x7fffffff;
  int rank = 0;
#pragma unroll
  for (int i = 0; i < RESC; ++i) {
    double di = sd[i]; int ji = sj[i];
    rank += (di < dq || (di == dq && ji < jq)) ? 1 : 0;
  }
  if (lane < RESC && rank < KI) {
    knn[((long)b * NT + n) * KI + rank] = jq;
    atomicAdd(&counts[(long)b * NCTX + jq], 1u);
  }
}

// ---------------- bf16 MFMA GEMM + bias, 3-term hi/lo split (node2edge linear) ----------------
__global__ __launch_bounds__(256) void k_gemm_mfma(const unsigned short* __restrict__ Ah,
                                                   const unsigned short* __restrict__ Al,
                                                   const unsigned short* __restrict__ WTh,
                                                   const unsigned short* __restrict__ WTl,
                                                   const float* __restrict__ bias,
                                                   float* __restrict__ out, int M) {
  __shared__ __bf16 ldsH[32 * CH];
  __shared__ __bf16 ldsL[32 * CH];
  const int b = blockIdx.y;
  const int m0 = blockIdx.x * 32;
  const int t = threadIdx.x, w = t >> 6, lane = t & 63;
  const int l31 = lane & 31, lh = lane >> 5;
  const long abase = (long)b * M * CH;
  const unsigned short* pH = Ah + abase + (long)(m0 + l31) * CH;
  const unsigned short* pL = Al + abase + (long)(m0 + l31) * CH;
#pragma unroll
  for (int r = 0; r < 4; ++r) {
    int c = r * 4 + w;
    __builtin_amdgcn_global_load_lds(
        (const __attribute__((address_space(1))) void*)(pH + (c * 2 + lh) * 8),
        (__attribute__((address_space(3))) void*)&ldsH[c * 512], 16, 0, 0);
    __builtin_amdgcn_global_load_lds(
        (const __attribute__((address_space(1))) void*)(pL + (c * 2 + lh) * 8),
        (__attribute__((address_space(3))) void*)&ldsL[c * 512], 16, 0, 0);
  }
  __syncthreads();

  const int n0 = w * 64;
  f32x16 acc0, acc1;
#pragma unroll
  for (int i = 0; i < 16; ++i) { acc0[i] = 0.f; acc1[i] = 0.f; }
#pragma unroll
  for (int s = 0; s < 16; ++s) {
    bf16x8 ah = *(const bf16x8*)&ldsH[s * 512 + lane * 8];
    bf16x8 al = *(const bf16x8*)&ldsL[s * 512 + lane * 8];
    const int koff = lh * 8 + s * 16;
    bf16x8 bh0 = *(const bf16x8*)&WTh[(n0 + l31) * CH + koff];
    bf16x8 bl0 = *(const bf16x8*)&WTl[(n0 + l31) * CH + koff];
    bf16x8 bh1 = *(const bf16x8*)&WTh[(n0 + 32 + l31) * CH + koff];
    bf16x8 bl1 = *(const bf16x8*)&WTl[(n0 + 32 + l31) * CH + koff];
    acc0 = __builtin_amdgcn_mfma_f32_32x32x16_bf16(ah, bh0, acc0, 0, 0, 0);
    acc1 = __builtin_amdgcn_mfma_f32_32x32x16_bf16(ah, bh1, acc1, 0, 0, 0);
    acc0 = __builtin_amdgcn_mfma_f32_32x32x16_bf16(ah, bl0, acc0, 0, 0, 0);
    acc1 = __builtin_amdgcn_mfma_f32_32x32x16_bf16(ah, bl1, acc1, 0, 0, 0);
    acc0 = __builtin_amdgcn_mfma_f32_32x32x16_bf16(al, bh0, acc0, 0, 0, 0);
    acc1 = __builtin_amdgcn_mfma_f32_32x32x16_bf16(al, bh1, acc1, 0, 0, 0);
  }
  float* ob = out + abase;
  float bi0 = bias[n0 + l31], bi1 = bias[n0 + 32 + l31];
#pragma unroll
  for (int reg = 0; reg < 16; ++reg) {
    int row = (reg & 3) + 8 * (reg >> 2) + 4 * lh;
    ob[(long)(m0 + row) * CH + n0 + l31]      = acc0[reg] + bi0;
    ob[(long)(m0 + row) * CH + n0 + 32 + l31] = acc1[reg] + bi1;
  }
}

// ---------------- gather-mean: X_edge = (Xn_t + sum_k Xn_c[knn]) / 9 -> bf16 hi/lo ----------------
__global__ __launch_bounds__(256) void k_gather(const float* __restrict__ Xn_t,
                                                const float* __restrict__ Xn_c,
                                                const int* __restrict__ knn,
                                                unsigned short* __restrict__ XeH,
                                                unsigned short* __restrict__ XeL) {
  const int n = blockIdx.x, b = blockIdx.y, c = threadIdx.x;
  const int* kn = knn + ((long)b * NT + n) * KI;
  int j[KI];
#pragma unroll
  for (int q = 0; q < KI; ++q) j[q] = kn[q];
  float acc = Xn_t[((long)b * NT + n) * CH + c];
#pragma unroll
  for (int q = 0; q < KI; ++q) acc += Xn_c[((long)b * NCTX + j[q]) * CH + c];
  float xe = acc / 9.0f;
  long o = ((long)b * NT + n) * CH + c;
  unsigned short h = bf16_rne(xe);
  XeH[o] = h;
  float hf = __uint_as_float((unsigned)h << 16);
  XeL[o] = bf16_rne(xe - hf);
}

// ---------------- fused edge2node GEMM + dual output (out_t direct + X_et rows) ----------------
// MFMA with a = WT2 rows (out-channels), b = Xe fragments -> C[ch][node]; epilogue adds bias,
// stores out_t image-layout coalesced, and LDS-pad transposes to R[node][ch] for scatter.
__global__ __launch_bounds__(256) void k_g2f(const unsigned short* __restrict__ XeH_g,
                                             const unsigned short* __restrict__ XeL_g,
                                             const unsigned short* __restrict__ WTh,
                                             const unsigned short* __restrict__ WTl,
                                             const float* __restrict__ bias,
                                             float* __restrict__ out_t,
                                             float* __restrict__ R) {
  __shared__ char smem[34816];   // phase A/B: 2x16KB Xe staging; phase C: float S[256][33]
  __bf16* ldsH = (__bf16*)smem;
  __bf16* ldsL = (__bf16*)(smem + 16384);
  const int b = blockIdx.y;
  const int m0 = blockIdx.x * 32;
  const int t = threadIdx.x, w = t >> 6, lane = t & 63;
  const int l31 = lane & 31, lh = lane >> 5;
  const long abase = (long)b * NT * CH;
  const unsigned short* pH = XeH_g + abase + (long)(m0 + l31) * CH;
  const unsigned short* pL = XeL_g + abase + (long)(m0 + l31) * CH;
#pragma unroll
  for (int r = 0; r < 4; ++r) {
    int c = r * 4 + w;
    __builtin_amdgcn_global_load_lds(
        (const __attribute__((address_space(1))) void*)(pH + (c * 2 + lh) * 8),
        (__attribute__((address_space(3))) void*)&ldsH[c * 512], 16, 0, 0);
    __builtin_amdgcn_global_load_lds(
        (const __attribute__((address_space(1))) void*)(pL + (c * 2 + lh) * 8),
        (__attribute__((address_space(3))) void*)&ldsL[c * 512], 16, 0, 0);
  }
  __syncthreads();

  const unsigned short* wh0 = WTh + (long)(w * 64 + l31) * CH;
  const unsigned short* wl0 = WTl + (long)(w * 64 + l31) * CH;
  f32x16 acc0, acc1;
#pragma unroll
  for (int i = 0; i < 16; ++i) { acc0[i] = 0.f; acc1[i] = 0.f; }
#pragma unroll
  for (int s = 0; s < 16; ++s) {
    const int koff = lh * 8 + s * 16;
    bf16x8 beh = *(const bf16x8*)&ldsH[s * 512 + lane * 8];
    bf16x8 bel = *(const bf16x8*)&ldsL[s * 512 + lane * 8];
    bf16x8 ah0 = *(const bf16x8*)(const __bf16*)(wh0 + koff);
    bf16x8 al0 = *(const bf16x8*)(const __bf16*)(wl0 + koff);
    bf16x8 ah1 = *(const bf16x8*)(const __bf16*)(wh0 + 32 * CH + koff);
    bf16x8 al1 = *(const bf16x8*)(const __bf16*)(wl0 + 32 * CH + koff);
    acc0 = __builtin_amdgcn_mfma_f32_32x32x16_bf16(ah0, beh, acc0, 0, 0, 0);
    acc1 = __builtin_amdgcn_mfma_f32_32x32x16_bf16(ah1, beh, acc1, 0, 0, 0);
    acc0 = __builtin_amdgcn_mfma_f32_32x32x16_bf16(al0, beh, acc0, 0, 0, 0);
    acc1 = __builtin_amdgcn_mfma_f32_32x32x16_bf16(al1, beh, acc1, 0, 0, 0);
    acc0 = __builtin_amdgcn_mfma_f32_32x32x16_bf16(ah0, bel, acc0, 0, 0, 0);
    acc1 = __builtin_amdgcn_mfma_f32_32x32x16_bf16(ah1, bel, acc1, 0, 0, 0);
  }
  __syncthreads();   // staging reads done; smem reusable

  float* S = (float*)smem;               // [256][33]
  float* ot = out_t + (long)b * CH * NT + m0;
#pragma unroll
  for (int reg = 0; reg < 16; ++reg) {
    const int row = (reg & 3) + 8 * (reg >> 2) + 4 * lh;
    const int ch0 = w * 64 + row, ch1 = ch0 + 32;
    float v0 = acc0[reg] + bias[ch0];
    float v1 = acc1[reg] + bias[ch1];
    S[ch0 * 33 + l31] = v0;
    S[ch1 * 33 + l31] = v1;
    ot[(long)ch0 * NT + l31] = v0;
    ot[(long)ch1 * NT + l31] = v1;
  }
  __syncthreads();
  const int n = t & 31, cg = t >> 5;
  float* rrow = R + ((long)b * NT + m0 + n) * CH;
#pragma unroll
  for (int kk = 0; kk < 8; ++kk) {
    const int c = cg * 32 + kk * 4;
    float4 v;
    v.x = S[(c + 0) * 33 + n];
    v.y = S[(c + 1) * 33 + n];
    v.z = S[(c + 2) * 33 + n];
    v.w = S[(c + 3) * 33 + n];
    *(float4*)(rrow + c) = v;
  }
}

// ---------------- scatter-add contributions to context nodes ----------------
__global__ __launch_bounds__(256) void k_scatter(const float* __restrict__ Xet,
                                                 const int* __restrict__ knn,
                                                 float* __restrict__ contrib) {
  const int n = blockIdx.x, b = blockIdx.y, c = threadIdx.x;
  const float v = Xet[((long)b * NT + n) * CH + c];
  const int* kn = knn + ((long)b * NT + n) * KI;
#pragma unroll
  for (int q = 0; q < KI; ++q)
    atomicAdd(&contrib[((long)b * NCTX + kn[q]) * CH + c], v);
}

// ---------------- finalize context outputs: divide by counts, transpose, split ----------------
__global__ __launch_bounds__(256) void k_fin_c(const float* __restrict__ contrib,
                                               const unsigned* __restrict__ counts,
                                               float* __restrict__ out1,
                                               float* __restrict__ out2) {
  __shared__ float tile[32][33];
  const int b = blockIdx.z;
  const int j0 = blockIdx.x * 32, c0 = blockIdx.y * 32;
  const int tx = threadIdx.x, ty = threadIdx.y;
#pragma unroll
  for (int i = ty; i < 32; i += 8) {
    float cnt = fmaxf((float)counts[(long)b * NCTX + j0 + i], 1.0f);
    tile[i][tx] = contrib[((long)b * NCTX + j0 + i) * CH + c0 + tx] / cnt;
  }
  __syncthreads();
  float* outp = (j0 < NT) ? (out1 + (long)b * CH * NT + j0)
                          : (out2 + (long)b * CH * NT + (j0 - NT));
#pragma unroll
  for (int i = ty; i < 32; i += 8)
    outp[(long)(c0 + i) * NT + tx] = tile[tx][i];
}

extern "C" void kernel_launch(void* const* d_in, const int* in_sizes, int n_in,
                              void* d_out, int out_size, void* d_ws, size_t ws_size,
                              hipStream_t stream) {
  const float* Xt  = (const float*)d_in[0];
  const float* Xc1 = (const float*)d_in[1];
  const float* Xc2 = (const float*)d_in[2];
  const float* W1  = (const float*)d_in[3];
  const float* b1  = (const float*)d_in[4];
  const float* W2  = (const float*)d_in[5];
  const float* b2  = (const float*)d_in[6];
  float* out = (float*)d_out;

  // ws layout (~68.4 MB)
  float* P = (float*)d_ws;                               // 33.55 MB  XcT -> Xn_c -> contrib
  float* Q = P + (long)BATCH * NCTX * CH;                // 16.78 MB  XtT -> XeH/XeL
  float* R = Q + (long)BATCH * NT * CH;                  // 16.78 MB  cand -> Xn_t -> X_et
  float* nrm = R + (long)BATCH * NT * CH;                // 128 KB
  unsigned* counts = (unsigned*)(nrm + (long)BATCH * NCTX);  // 128 KB
  int* knn = (int*)(counts + (long)BATCH * NCTX);        // 512 KB
  unsigned short* WT1h = (unsigned short*)(knn + (long)BATCH * NT * KI);
  unsigned short* WT1l = WT1h + CH * CH;
  unsigned short* WT2h = WT1l + CH * CH;
  unsigned short* WT2l = WT2h + CH * CH;                 // 4 x 128 KB

  unsigned* cand = (unsigned*)R;   // 5.24 MB, dead before gemm1 writes Xn_t to R

  unsigned short* XcBh = (unsigned short*)d_out;
  unsigned short* XtBh = XcBh + (long)BATCH * NCTX * CH;
  unsigned short* XcBl = XtBh + (long)BATCH * NT * CH;
  unsigned short* XtBl = XcBl + (long)BATCH * NCTX * CH;

  float* Xn_c = P;
  float* Xn_t = R;
  unsigned short* XeH = (unsigned short*)Q;   // after rescore, Q (XtT) is dead
  unsigned short* XeL = XeH + (long)BATCH * NT * CH;

  float* out_t  = out;             // overwrites dead XcBh region (after gemm1 reads)
  float* out_c1 = out + (long)BATCH * CH * NT;
  float* out_c2 = out + 2L * BATCH * CH * NT;

  dim3 tb(32, 8);

  hipMemsetAsync(nrm, 0, (size_t)BATCH * NCTX * 8, stream);   // nrm + counts

  k_wtrans<<<dim3(8, 8, 2), tb, 0, stream>>>(W1, W2, WT1h, WT1l, WT2h, WT2l);

  k_transpose2<<<dim3(NT / 32, CH / 64, 12), tb, 0, stream>>>(
      Xt, Xc1, Xc2, Q, P, XtBh, XtBl, XcBh, XcBl, nrm);

  k_dist_mfma<<<dim3(8 * 16 * DNSPLIT), 256, 0, stream>>>(
      (const __bf16*)XcBh, (const __bf16*)XtBh, nrm, cand);

  k_rescore<<<dim3(NT, BATCH), 64, 0, stream>>>(Q, P, cand, knn, counts);

  // node2edge linear (bf16 MFMA, 3-term): Xn_t -> R, Xn_c -> P
  k_gemm_mfma<<<dim3(NT / 32, BATCH), 256, 0, stream>>>(XtBh, XtBl, WT1h, WT1l, b1, Xn_t, NT);
  k_gemm_mfma<<<dim3(NCTX / 32, BATCH), 256, 0, stream>>>(XcBh, XcBl, WT1h, WT1l, b1, Xn_c, NCTX);

  // edge mean-pool -> Q as bf16 hi/lo (P still live as Xn_c)
  k_gather<<<dim3(NT, BATCH), 256, 0, stream>>>(Xn_t, Xn_c, knn, XeH, XeL);

  // P dead now -> becomes contrib
  hipMemsetAsync(P, 0, (size_t)BATCH * NCTX * CH * 4, stream);

  // fused edge2node + out_t + X_et rows (in R)
  k_g2f<<<dim3(NT / 32, BATCH), 256, 0, stream>>>(XeH, XeL, WT2h, WT2l, b2, out_t, R);

  // context scatter-mean
  k_scatter<<<dim3(NT, BATCH), 256, 0, stream>>>(R, knn, P);
  k_fin_c<<<dim3(NCTX / 32, CH / 32, BATCH), tb, 0, stream>>>(P, counts, out_c1, out_c2);
}

// Round 12
// 399.789 us; speedup vs baseline: 1.2113x; 1.0934x over previous
//
#include <hip/hip_runtime.h>
#include <math.h>
#include <float.h>

#define BATCH 4
#define CH    256
#define NT    4096
#define NCTX  8192
#define KI    8

// coarse-selection geometry
#define CSEL    10                 // per-split top-C after lane-half merge (>=8+2 slack => safe)
#define DNSPLIT 8                  // ctx splits
#define CTX_PER (NCTX / DNSPLIT)   // 1024
#define NTILE   (CTX_PER / 32)     // 32 tiles of 32 ctx
#define NKEY    (DNSPLIT * CSEL)   // 80 packed keys per target
#define RESC    12                 // keys kept for exact fp64 rescore

typedef __attribute__((ext_vector_type(8)))  __bf16 bf16x8;
typedef __attribute__((ext_vector_type(16))) float  f32x16;

__device__ __forceinline__ unsigned short bf16_rne(float v) {
  unsigned u = __float_as_uint(v);
  return (unsigned short)((u + 0x7fffu + ((u >> 16) & 1u)) >> 16);
}

// ---------------- prep: transpose (128-ch tiles, wide stores) + W transpose, role-fused ----------------
// bid < 3072: transpose role: x=bid&127 (m-tile), y=(bid>>7)&1 (c-group of 128), z=bid>>8 (which*4+b)
// else: wtrans role (128 blocks).
__global__ __launch_bounds__(256) void k_prep(const float* __restrict__ Xt,
                                              const float* __restrict__ Xc1,
                                              const float* __restrict__ Xc2,
                                              float* __restrict__ Q,
                                              float* __restrict__ P,
                                              unsigned short* __restrict__ XtBh,
                                              unsigned short* __restrict__ XtBl,
                                              unsigned short* __restrict__ XcBh,
                                              unsigned short* __restrict__ XcBl,
                                              float* __restrict__ nrm,
                                              const float* __restrict__ W1,
                                              const float* __restrict__ W2,
                                              unsigned short* __restrict__ WT1h,
                                              unsigned short* __restrict__ WT1l,
                                              unsigned short* __restrict__ WT2h,
                                              unsigned short* __restrict__ WT2l) {
  __shared__ float tile[128][33];   // 16.9 KB
  __shared__ float ps[8][32];
  const int bid = blockIdx.x;
  const int tx = threadIdx.x, ty = threadIdx.y;

  if (bid < 3072) {
    const int x = bid & 127, y = (bid >> 7) & 1, z = bid >> 8;
    const int which = z >> 2, b = z & 3;
    const float* src;
    float* dF; unsigned short *dH, *dL; float* nrmp = nullptr;
    if (which == 0) {
      src = Xt + (long)b * CH * NT;
      dF = Q + (long)b * NT * CH;
      dH = XtBh + (long)b * NT * CH;  dL = XtBl + (long)b * NT * CH;
    } else if (which == 1) {
      src = Xc1 + (long)b * CH * NT;
      dF = P + (long)b * NCTX * CH;
      dH = XcBh + (long)b * NCTX * CH;  dL = XcBl + (long)b * NCTX * CH;
      nrmp = nrm + (long)b * NCTX;
    } else {
      src = Xc2 + (long)b * CH * NT;
      dF = P + ((long)b * NCTX + NT) * CH;
      dH = XcBh + ((long)b * NCTX + NT) * CH;  dL = XcBl + ((long)b * NCTX + NT) * CH;
      nrmp = nrm + (long)b * NCTX + NT;
    }
    const int m0 = x * 32, c0 = y * 128;
    float part = 0.f;
#pragma unroll
    for (int i = ty; i < 128; i += 8) {
      float v = src[(long)(c0 + i) * NT + (m0 + tx)];
      tile[i][tx] = v;
      part = fmaf(v, v, part);
    }
    if (which) ps[ty][tx] = part;
    __syncthreads();
#pragma unroll
    for (int i = ty; i < 32; i += 8) {
      float v0 = tile[4 * tx + 0][i];
      float v1 = tile[4 * tx + 1][i];
      float v2 = tile[4 * tx + 2][i];
      float v3 = tile[4 * tx + 3][i];
      long o = (long)(m0 + i) * CH + (c0 + 4 * tx);
      float4 f4; f4.x = v0; f4.y = v1; f4.z = v2; f4.w = v3;
      *(float4*)&dF[o] = f4;
      unsigned short h0 = bf16_rne(v0), h1 = bf16_rne(v1), h2 = bf16_rne(v2), h3 = bf16_rne(v3);
      ushort4 h4; h4.x = h0; h4.y = h1; h4.z = h2; h4.w = h3;
      *(ushort4*)&dH[o] = h4;
      ushort4 l4;
      l4.x = bf16_rne(v0 - __uint_as_float((unsigned)h0 << 16));
      l4.y = bf16_rne(v1 - __uint_as_float((unsigned)h1 << 16));
      l4.z = bf16_rne(v2 - __uint_as_float((unsigned)h2 << 16));
      l4.w = bf16_rne(v3 - __uint_as_float((unsigned)h3 << 16));
      *(ushort4*)&dL[o] = l4;
    }
    if (which && ty == 0) {
      float s = 0.f;
#pragma unroll
      for (int j = 0; j < 8; ++j) s += ps[j][tx];
      atomicAdd(&nrmp[m0 + tx], -0.5f * s);
    }
  } else {
    const int r = bid - 3072;
    const int n0 = (r & 7) * 32, k0 = ((r >> 3) & 7) * 32;
    const float* W = (r >> 6) ? W2 : W1;
    unsigned short* WTh = (r >> 6) ? WT2h : WT1h;
    unsigned short* WTl = (r >> 6) ? WT2l : WT1l;
#pragma unroll
    for (int i = ty; i < 32; i += 8)
      tile[i][tx] = W[(k0 + i) * CH + (n0 + tx)];
    __syncthreads();
#pragma unroll
    for (int i = ty; i < 32; i += 8) {
      float v = tile[tx][i];
      int o = (n0 + i) * CH + (k0 + tx);
      unsigned short h = bf16_rne(v);
      WTh[o] = h;
      WTl[o] = bf16_rne(v - __uint_as_float((unsigned)h << 16));
    }
  }
}

// ---------------- main: MFMA coarse scorer (blocks 0..1023) + optional node2edge GEMM role ----------------
// dist: lid=(b*2+jh)+8*(jw+16*split), XCD-swizzled; unguarded 10-deep packed-key bubble.
// gemm role (blocks >= 1024, only in fat mode): 3-term hi/lo bf16 MFMA, out = A@W1 + b1.
__global__ __launch_bounds__(256) void k_main(const __bf16* __restrict__ XcB,
                                              const __bf16* __restrict__ XtB,
                                              const float* __restrict__ nrm,
                                              unsigned* __restrict__ cand,
                                              const unsigned short* __restrict__ XtBh,
                                              const unsigned short* __restrict__ XtBl,
                                              const unsigned short* __restrict__ XcBh,
                                              const unsigned short* __restrict__ XcBl,
                                              const unsigned short* __restrict__ WTh,
                                              const unsigned short* __restrict__ WTl,
                                              const float* __restrict__ bias,
                                              float* __restrict__ outT,
                                              float* __restrict__ outC) {
  __shared__ __bf16 lds[2][32 * CH];   // 32 KB, shared by both roles
  const int bid = blockIdx.x;
  const int t = threadIdx.x, w = t >> 6, lane = t & 63;
  const int l31 = lane & 31, lh = lane >> 5;

  if (bid < 1024) {
    // ---- dist role ----
    const int xk = bid & 7;
    const int b = xk >> 1, jh = xk & 1;
    const int jw = (bid >> 3) & 15, split = bid >> 7;
    const int tgt0 = (jh * 16 + jw) * 128 + w * 32;
    const int cbase = split * CTX_PER;
    const float* nrmt = nrm + (long)b * NCTX + cbase;

    const __bf16* tp = XtB + ((long)b * NT + tgt0 + l31) * CH + lh * 8;
    bf16x8 bfrag[16];
#pragma unroll
    for (int s = 0; s < 16; ++s) bfrag[s] = *(const bf16x8*)(tp + s * 16);

    unsigned kd[CSEL];
#pragma unroll
    for (int q = 0; q < CSEL; ++q) kd[q] = 0xFFFFFFFFu;

    const __bf16* cp = XcB + ((long)b * NCTX + cbase + l31) * CH;

    auto STAGE = [&](int buf, int jt) {
#pragma unroll
      for (int r = 0; r < 4; ++r) {
        int c = r * 4 + w;
        const __bf16* src = cp + (long)jt * 32 * CH + (c * 2 + lh) * 8;
        __bf16* dst = &lds[buf][c * 512];
        __builtin_amdgcn_global_load_lds((const __attribute__((address_space(1))) void*)src,
                                         (__attribute__((address_space(3))) void*)dst,
                                         16, 0, 0);
      }
    };

    STAGE(0, 0);
    __syncthreads();

    int cur = 0;
    for (int jt = 0; jt < NTILE; ++jt) {
      if (jt + 1 < NTILE) STAGE(cur ^ 1, jt + 1);

      const int ct0 = jt * 32;
      f32x16 acc;
#pragma unroll
      for (int g = 0; g < 4; ++g) {
        float4 nv = *(const float4*)&nrmt[ct0 + 8 * g + 4 * lh];
        acc[4 * g + 0] = nv.x; acc[4 * g + 1] = nv.y;
        acc[4 * g + 2] = nv.z; acc[4 * g + 3] = nv.w;
      }
#pragma unroll
      for (int s = 0; s < 16; ++s) {
        bf16x8 a = *(const bf16x8*)(&lds[cur][s * 512 + lane * 8]);
        acc = __builtin_amdgcn_mfma_f32_32x32x16_bf16(a, bfrag[s], acc, 0, 0, 0);
      }

#pragma unroll
      for (int reg = 0; reg < 16; ++reg) {
        const int row = (reg & 3) + 8 * (reg >> 2) + lh * 4;
        float sc = fmaf(acc[reg], -2.0f, 512.0f);
        unsigned key = (__float_as_uint(sc) & 0xFFFFF800u) | (unsigned)ct0 | (unsigned)row;
#pragma unroll
        for (int q = 0; q < CSEL; ++q) {
          unsigned lo = min(key, kd[q]);
          key = max(key, kd[q]);
          kd[q] = lo;
        }
      }
      __syncthreads();
      cur ^= 1;
    }

    unsigned oth[CSEL];
#pragma unroll
    for (int q = 0; q < CSEL; ++q) oth[q] = (unsigned)__shfl_xor((int)kd[q], 32, 64);
    if (lh == 0) {
      long ob = (((long)b * NT + tgt0 + l31) * DNSPLIT + split) * CSEL;
#pragma unroll
      for (int q = 0; q < CSEL; ++q)
        cand[ob + q] = min(kd[q], oth[CSEL - 1 - q]);
    }
  } else {
    // ---- gemm role (fat mode only) ----
    int g = bid - 1024;
    const unsigned short *Ah, *Al; float* out; int M, m0, b;
    if (g < 512) { Ah = XtBh; Al = XtBl; out = outT; M = NT;   m0 = (g & 127) * 32; b = g >> 7; }
    else { g -= 512; Ah = XcBh; Al = XcBl; out = outC; M = NCTX; m0 = (g & 255) * 32; b = g >> 8; }
    __bf16* ldsH = lds[0];
    __bf16* ldsL = lds[1];
    const long abase = (long)b * M * CH;
    const unsigned short* pH = Ah + abase + (long)(m0 + l31) * CH;
    const unsigned short* pL = Al + abase + (long)(m0 + l31) * CH;
#pragma unroll
    for (int r = 0; r < 4; ++r) {
      int c = r * 4 + w;
      __builtin_amdgcn_global_load_lds(
          (const __attribute__((address_space(1))) void*)(pH + (c * 2 + lh) * 8),
          (__attribute__((address_space(3))) void*)&ldsH[c * 512], 16, 0, 0);
      __builtin_amdgcn_global_load_lds(
          (const __attribute__((address_space(1))) void*)(pL + (c * 2 + lh) * 8),
          (__attribute__((address_space(3))) void*)&ldsL[c * 512], 16, 0, 0);
    }
    __syncthreads();

    const int n0 = w * 64;
    f32x16 acc0, acc1;
#pragma unroll
    for (int i = 0; i < 16; ++i) { acc0[i] = 0.f; acc1[i] = 0.f; }
#pragma unroll
    for (int s = 0; s < 16; ++s) {
      bf16x8 ah = *(const bf16x8*)&ldsH[s * 512 + lane * 8];
      bf16x8 al = *(const bf16x8*)&ldsL[s * 512 + lane * 8];
      const int koff = lh * 8 + s * 16;
      bf16x8 bh0 = *(const bf16x8*)&WTh[(n0 + l31) * CH + koff];
      bf16x8 bl0 = *(const bf16x8*)&WTl[(n0 + l31) * CH + koff];
      bf16x8 bh1 = *(const bf16x8*)&WTh[(n0 + 32 + l31) * CH + koff];
      bf16x8 bl1 = *(const bf16x8*)&WTl[(n0 + 32 + l31) * CH + koff];
      acc0 = __builtin_amdgcn_mfma_f32_32x32x16_bf16(ah, bh0, acc0, 0, 0, 0);
      acc1 = __builtin_amdgcn_mfma_f32_32x32x16_bf16(ah, bh1, acc1, 0, 0, 0);
      acc0 = __builtin_amdgcn_mfma_f32_32x32x16_bf16(ah, bl0, acc0, 0, 0, 0);
      acc1 = __builtin_amdgcn_mfma_f32_32x32x16_bf16(ah, bl1, acc1, 0, 0, 0);
      acc0 = __builtin_amdgcn_mfma_f32_32x32x16_bf16(al, bh0, acc0, 0, 0, 0);
      acc1 = __builtin_amdgcn_mfma_f32_32x32x16_bf16(al, bh1, acc1, 0, 0, 0);
    }
    float* ob = out + abase;
    float bi0 = bias[n0 + l31], bi1 = bias[n0 + 32 + l31];
#pragma unroll
    for (int reg = 0; reg < 16; ++reg) {
      int row = (reg & 3) + 8 * (reg >> 2) + 4 * lh;
      ob[(long)(m0 + row) * CH + n0 + l31]      = acc0[reg] + bi0;
      ob[(long)(m0 + row) * CH + n0 + 32 + l31] = acc1[reg] + bi1;
    }
  }
}

// ---------------- standalone node2edge GEMM (fallback mode) ----------------
__global__ __launch_bounds__(256) void k_gemm_mfma(const unsigned short* __restrict__ Ah,
                                                   const unsigned short* __restrict__ Al,
                                                   const unsigned short* __restrict__ WTh,
                                                   const unsigned short* __restrict__ WTl,
                                                   const float* __restrict__ bias,
                                                   float* __restrict__ out, int M) {
  __shared__ __bf16 ldsH[32 * CH];
  __shared__ __bf16 ldsL[32 * CH];
  const int b = blockIdx.y;
  const int m0 = blockIdx.x * 32;
  const int t = threadIdx.x, w = t >> 6, lane = t & 63;
  const int l31 = lane & 31, lh = lane >> 5;
  const long abase = (long)b * M * CH;
  const unsigned short* pH = Ah + abase + (long)(m0 + l31) * CH;
  const unsigned short* pL = Al + abase + (long)(m0 + l31) * CH;
#pragma unroll
  for (int r = 0; r < 4; ++r) {
    int c = r * 4 + w;
    __builtin_amdgcn_global_load_lds(
        (const __attribute__((address_space(1))) void*)(pH + (c * 2 + lh) * 8),
        (__attribute__((address_space(3))) void*)&ldsH[c * 512], 16, 0, 0);
    __builtin_amdgcn_global_load_lds(
        (const __attribute__((address_space(1))) void*)(pL + (c * 2 + lh) * 8),
        (__attribute__((address_space(3))) void*)&ldsL[c * 512], 16, 0, 0);
  }
  __syncthreads();

  const int n0 = w * 64;
  f32x16 acc0, acc1;
#pragma unroll
  for (int i = 0; i < 16; ++i) { acc0[i] = 0.f; acc1[i] = 0.f; }
#pragma unroll
  for (int s = 0; s < 16; ++s) {
    bf16x8 ah = *(const bf16x8*)&ldsH[s * 512 + lane * 8];
    bf16x8 al = *(const bf16x8*)&ldsL[s * 512 + lane * 8];
    const int koff = lh * 8 + s * 16;
    bf16x8 bh0 = *(const bf16x8*)&WTh[(n0 + l31) * CH + koff];
    bf16x8 bl0 = *(const bf16x8*)&WTl[(n0 + l31) * CH + koff];
    bf16x8 bh1 = *(const bf16x8*)&WTh[(n0 + 32 + l31) * CH + koff];
    bf16x8 bl1 = *(const bf16x8*)&WTl[(n0 + 32 + l31) * CH + koff];
    acc0 = __builtin_amdgcn_mfma_f32_32x32x16_bf16(ah, bh0, acc0, 0, 0, 0);
    acc1 = __builtin_amdgcn_mfma_f32_32x32x16_bf16(ah, bh1, acc1, 0, 0, 0);
    acc0 = __builtin_amdgcn_mfma_f32_32x32x16_bf16(ah, bl0, acc0, 0, 0, 0);
    acc1 = __builtin_amdgcn_mfma_f32_32x32x16_bf16(ah, bl1, acc1, 0, 0, 0);
    acc0 = __builtin_amdgcn_mfma_f32_32x32x16_bf16(al, bh0, acc0, 0, 0, 0);
    acc1 = __builtin_amdgcn_mfma_f32_32x32x16_bf16(al, bh1, acc1, 0, 0, 0);
  }
  float* ob = out + abase;
  float bi0 = bias[n0 + l31], bi1 = bias[n0 + 32 + l31];
#pragma unroll
  for (int reg = 0; reg < 16; ++reg) {
    int row = (reg & 3) + 8 * (reg >> 2) + 4 * lh;
    ob[(long)(m0 + row) * CH + n0 + l31]      = acc0[reg] + bi0;
    ob[(long)(m0 + row) * CH + n0 + 32 + l31] = acc1[reg] + bi1;
  }
}

// ---------------- rescore: coarse top-RESC of 80 keys, fp64 exact, rank-8 + counts ----------------
__global__ __launch_bounds__(64) void k_rescore(const float* __restrict__ XtT,
                                                const float* __restrict__ XcT,
                                                const unsigned* __restrict__ cand,
                                                int* __restrict__ knn,
                                                unsigned* __restrict__ counts) {
  const int n = blockIdx.x, b = blockIdx.y, lane = threadIdx.x;
  const int grp = lane >> 4, gl = lane & 15;
  __shared__ unsigned sk[NKEY];
  __shared__ int cidx[RESC];
  __shared__ double sd[RESC];
  __shared__ int sj[RESC];
  const unsigned* kp = cand + ((long)b * NT + n) * NKEY;
  unsigned k0 = kp[lane];
  unsigned k1 = (lane < NKEY - 64) ? kp[64 + lane] : 0xFFFFFFFFu;
  sk[lane] = k0;
  if (lane < NKEY - 64) sk[64 + lane] = k1;
  __syncthreads();
  int r0 = 0, r1 = 0;
  for (int i = 0; i < NKEY; ++i) {
    unsigned s = sk[i];
    r0 += (s < k0 || (s == k0 && i < lane)) ? 1 : 0;
    r1 += (s < k1 || (s == k1 && i < 64 + lane)) ? 1 : 0;
  }
  if (r0 < RESC) cidx[r0] = (lane / CSEL) * CTX_PER + (int)(k0 & 0x7FFu);
  if (lane < NKEY - 64 && r1 < RESC)
    cidx[r1] = ((64 + lane) / CSEL) * CTX_PER + (int)(k1 & 0x7FFu);
  __syncthreads();

  const float* xt = XtT + ((long)b * NT + n) * CH + gl * 16;
  double xa[16];
#pragma unroll
  for (int r = 0; r < 4; ++r) {
    float4 v = *(const float4*)(xt + r * 4);
    xa[4 * r + 0] = (double)v.x; xa[4 * r + 1] = (double)v.y;
    xa[4 * r + 2] = (double)v.z; xa[4 * r + 3] = (double)v.w;
  }
#pragma unroll
  for (int q0 = 0; q0 < RESC; q0 += 4) {
    int q = q0 + grp;
    int j = cidx[q];
    const float* xc = XcT + ((long)b * NCTX + j) * CH + gl * 16;
    double acc = 0.0;
#pragma unroll
    for (int r = 0; r < 4; ++r) {
      float4 v = *(const float4*)(xc + r * 4);
      double d0 = xa[4 * r + 0] - (double)v.x; acc = fma(d0, d0, acc);
      double d1 = xa[4 * r + 1] - (double)v.y; acc = fma(d1, d1, acc);
      double d2 = xa[4 * r + 2] - (double)v.z; acc = fma(d2, d2, acc);
      double d3 = xa[4 * r + 3] - (double)v.w; acc = fma(d3, d3, acc);
    }
#pragma unroll
    for (int off = 8; off > 0; off >>= 1) acc += __shfl_xor(acc, off, 64);
    if (gl == 0) { sd[q] = acc; sj[q] = j; }
  }
  __syncthreads();
  double dq = (lane < RESC) ? sd[lane] : DBL_MAX;
  int    jq = (lane < RESC) ? sj[lane] : 0x7fffffff;
  int rank = 0;
#pragma unroll
  for (int i = 0; i < RESC; ++i) {
    double di = sd[i]; int ji = sj[i];
    rank += (di < dq || (di == dq && ji < jq)) ? 1 : 0;
  }
  if (lane < RESC && rank < KI) {
    knn[((long)b * NT + n) * KI + rank] = jq;
    atomicAdd(&counts[(long)b * NCTX + jq], 1u);
  }
}

// ---------------- gather-mean: X_edge = (Xn_t + sum_k Xn_c[knn]) / 9 -> bf16 hi/lo ----------------
__global__ __launch_bounds__(256) void k_gather(const float* __restrict__ Xn_t,
                                                const float* __restrict__ Xn_c,
                                                const int* __restrict__ knn,
                                                unsigned short* __restrict__ XeH,
                                                unsigned short* __restrict__ XeL) {
  const int n = blockIdx.x, b = blockIdx.y, c = threadIdx.x;
  const int* kn = knn + ((long)b * NT + n) * KI;
  int j[KI];
#pragma unroll
  for (int q = 0; q < KI; ++q) j[q] = kn[q];
  float acc = Xn_t[((long)b * NT + n) * CH + c];
#pragma unroll
  for (int q = 0; q < KI; ++q) acc += Xn_c[((long)b * NCTX + j[q]) * CH + c];
  float xe = acc / 9.0f;
  long o = ((long)b * NT + n) * CH + c;
  unsigned short h = bf16_rne(xe);
  XeH[o] = h;
  XeL[o] = bf16_rne(xe - __uint_as_float((unsigned)h << 16));
}

// ---------------- fused edge2node GEMM + dual output (out_t direct + X_et rows) ----------------
__global__ __launch_bounds__(256) void k_g2f(const unsigned short* __restrict__ XeH_g,
                                             const unsigned short* __restrict__ XeL_g,
                                             const unsigned short* __restrict__ WTh,
                                             const unsigned short* __restrict__ WTl,
                                             const float* __restrict__ bias,
                                             float* __restrict__ out_t,
                                             float* __restrict__ R) {
  __shared__ char smem[34816];   // phase A/B: 2x16KB Xe staging; phase C: float S[256][33]
  __bf16* ldsH = (__bf16*)smem;
  __bf16* ldsL = (__bf16*)(smem + 16384);
  const int b = blockIdx.y;
  const int m0 = blockIdx.x * 32;
  const int t = threadIdx.x, w = t >> 6, lane = t & 63;
  const int l31 = lane & 31, lh = lane >> 5;
  const long abase = (long)b * NT * CH;
  const unsigned short* pH = XeH_g + abase + (long)(m0 + l31) * CH;
  const unsigned short* pL = XeL_g + abase + (long)(m0 + l31) * CH;
#pragma unroll
  for (int r = 0; r < 4; ++r) {
    int c = r * 4 + w;
    __builtin_amdgcn_global_load_lds(
        (const __attribute__((address_space(1))) void*)(pH + (c * 2 + lh) * 8),
        (__attribute__((address_space(3))) void*)&ldsH[c * 512], 16, 0, 0);
    __builtin_amdgcn_global_load_lds(
        (const __attribute__((address_space(1))) void*)(pL + (c * 2 + lh) * 8),
        (__attribute__((address_space(3))) void*)&ldsL[c * 512], 16, 0, 0);
  }
  __syncthreads();

  const unsigned short* wh0 = WTh + (long)(w * 64 + l31) * CH;
  const unsigned short* wl0 = WTl + (long)(w * 64 + l31) * CH;
  f32x16 acc0, acc1;
#pragma unroll
  for (int i = 0; i < 16; ++i) { acc0[i] = 0.f; acc1[i] = 0.f; }
#pragma unroll
  for (int s = 0; s < 16; ++s) {
    const int koff = lh * 8 + s * 16;
    bf16x8 beh = *(const bf16x8*)&ldsH[s * 512 + lane * 8];
    bf16x8 bel = *(const bf16x8*)&ldsL[s * 512 + lane * 8];
    bf16x8 ah0 = *(const bf16x8*)(const __bf16*)(wh0 + koff);
    bf16x8 al0 = *(const bf16x8*)(const __bf16*)(wl0 + koff);
    bf16x8 ah1 = *(const bf16x8*)(const __bf16*)(wh0 + 32 * CH + koff);
    bf16x8 al1 = *(const bf16x8*)(const __bf16*)(wl0 + 32 * CH + koff);
    acc0 = __builtin_amdgcn_mfma_f32_32x32x16_bf16(ah0, beh, acc0, 0, 0, 0);
    acc1 = __builtin_amdgcn_mfma_f32_32x32x16_bf16(ah1, beh, acc1, 0, 0, 0);
    acc0 = __builtin_amdgcn_mfma_f32_32x32x16_bf16(al0, beh, acc0, 0, 0, 0);
    acc1 = __builtin_amdgcn_mfma_f32_32x32x16_bf16(al1, beh, acc1, 0, 0, 0);
    acc0 = __builtin_amdgcn_mfma_f32_32x32x16_bf16(ah0, bel, acc0, 0, 0, 0);
    acc1 = __builtin_amdgcn_mfma_f32_32x32x16_bf16(ah1, bel, acc1, 0, 0, 0);
  }
  __syncthreads();

  float* S = (float*)smem;               // [256][33]
  float* ot = out_t + (long)b * CH * NT + m0;
#pragma unroll
  for (int reg = 0; reg < 16; ++reg) {
    const int row = (reg & 3) + 8 * (reg >> 2) + 4 * lh;
    const int ch0 = w * 64 + row, ch1 = ch0 + 32;
    float v0 = acc0[reg] + bias[ch0];
    float v1 = acc1[reg] + bias[ch1];
    S[ch0 * 33 + l31] = v0;
    S[ch1 * 33 + l31] = v1;
    ot[(long)ch0 * NT + l31] = v0;
    ot[(long)ch1 * NT + l31] = v1;
  }
  __syncthreads();
  const int n = t & 31, cg = t >> 5;
  float* rrow = R + ((long)b * NT + m0 + n) * CH;
#pragma unroll
  for (int kk = 0; kk < 8; ++kk) {
    const int c = cg * 32 + kk * 4;
    float4 v;
    v.x = S[(c + 0) * 33 + n];
    v.y = S[(c + 1) * 33 + n];
    v.z = S[(c + 2) * 33 + n];
    v.w = S[(c + 3) * 33 + n];
    *(float4*)(rrow + c) = v;
  }
}

// ---------------- scatter-add contributions to context nodes ----------------
__global__ __launch_bounds__(256) void k_scatter(const float* __restrict__ Xet,
                                                 const int* __restrict__ knn,
                                                 float* __restrict__ contrib) {
  const int n = blockIdx.x, b = blockIdx.y, c = threadIdx.x;
  const float v = Xet[((long)b * NT + n) * CH + c];
  const int* kn = knn + ((long)b * NT + n) * KI;
#pragma unroll
  for (int q = 0; q < KI; ++q)
    atomicAdd(&contrib[((long)b * NCTX + kn[q]) * CH + c], v);
}

// ---------------- finalize context outputs: /counts, transpose (128-j tiles, float4 stores) ----------------
__global__ __launch_bounds__(256) void k_fin_c(const float* __restrict__ contrib,
                                               const unsigned* __restrict__ counts,
                                               float* __restrict__ out1,
                                               float* __restrict__ out2) {
  __shared__ float tile[128][33];
  const int b = blockIdx.z;
  const int j0 = blockIdx.x * 128, c0 = blockIdx.y * 32;
  const int tx = threadIdx.x, ty = threadIdx.y;
#pragma unroll
  for (int i = ty; i < 128; i += 8) {
    float cnt = fmaxf((float)counts[(long)b * NCTX + j0 + i], 1.0f);
    tile[i][tx] = contrib[((long)b * NCTX + j0 + i) * CH + c0 + tx] * (1.0f / cnt);
  }
  __syncthreads();
  float* outp = (j0 < NT) ? (out1 + (long)b * CH * NT + j0)
                          : (out2 + (long)b * CH * NT + (j0 - NT));
#pragma unroll
  for (int i = ty; i < 32; i += 8) {
    float4 v;
    v.x = tile[4 * tx + 0][i];
    v.y = tile[4 * tx + 1][i];
    v.z = tile[4 * tx + 2][i];
    v.w = tile[4 * tx + 3][i];
    *(float4*)&outp[(long)(c0 + i) * NT + 4 * tx] = v;
  }
}

extern "C" void kernel_launch(void* const* d_in, const int* in_sizes, int n_in,
                              void* d_out, int out_size, void* d_ws, size_t ws_size,
                              hipStream_t stream) {
  const float* Xt  = (const float*)d_in[0];
  const float* Xc1 = (const float*)d_in[1];
  const float* Xc2 = (const float*)d_in[2];
  const float* W1  = (const float*)d_in[3];
  const float* b1  = (const float*)d_in[4];
  const float* W2  = (const float*)d_in[5];
  const float* b2  = (const float*)d_in[6];
  float* out = (float*)d_out;

  // common ws layout (68.42 MB)
  float* P = (float*)d_ws;                               // XcT -> (fallback Xn_c) -> contrib
  float* Q = P + (long)BATCH * NCTX * CH;                // XtT -> XeH/XeL
  float* R = Q + (long)BATCH * NT * CH;                  // (fallback cand) -> Xn_t -> X_et
  float* nrm = R + (long)BATCH * NT * CH;
  unsigned* counts = (unsigned*)(nrm + (long)BATCH * NCTX);
  int* knn = (int*)(counts + (long)BATCH * NCTX);
  unsigned short* WT1h = (unsigned short*)(knn + (long)BATCH * NT * KI);
  unsigned short* WT1l = WT1h + CH * CH;
  unsigned short* WT2h = WT1l + CH * CH;
  unsigned short* WT2l = WT2h + CH * CH;
  // fat-mode extras: separate Xn_c (33.55 MB) + cand (5.24 MB)
  float* Xn_c_fat = (float*)(WT2l + CH * CH);
  unsigned* cand_fat = (unsigned*)(Xn_c_fat + (long)BATCH * NCTX * CH);
  const size_t need_fat = (size_t)((char*)(cand_fat + (long)BATCH * NT * NKEY) - (char*)d_ws);
  const bool fat = ws_size >= need_fat;

  unsigned* cand = fat ? cand_fat : (unsigned*)R;
  float* Xn_c = fat ? Xn_c_fat : P;
  float* Xn_t = R;

  unsigned short* XcBh = (unsigned short*)d_out;
  unsigned short* XtBh = XcBh + (long)BATCH * NCTX * CH;
  unsigned short* XcBl = XtBh + (long)BATCH * NT * CH;
  unsigned short* XtBl = XcBl + (long)BATCH * NCTX * CH;

  unsigned short* XeH = (unsigned short*)Q;   // after rescore, Q (XtT) is dead
  unsigned short* XeL = XeH + (long)BATCH * NT * CH;

  float* out_t  = out;             // overwrites dead XcBh region
  float* out_c1 = out + (long)BATCH * CH * NT;
  float* out_c2 = out + 2L * BATCH * CH * NT;

  dim3 tb(32, 8);

  hipMemsetAsync(nrm, 0, (size_t)BATCH * NCTX * 8, stream);   // nrm + counts

  // transposes + W prep (fused)
  k_prep<<<dim3(3072 + 128), tb, 0, stream>>>(Xt, Xc1, Xc2, Q, P, XtBh, XtBl, XcBh, XcBl, nrm,
                                              W1, W2, WT1h, WT1l, WT2h, WT2l);

  if (fat) {
    // dist + both node2edge GEMMs in one launch (independent; gemm fills dist's idle slots)
    k_main<<<dim3(1024 + 512 + 1024), 256, 0, stream>>>(
        (const __bf16*)XcBh, (const __bf16*)XtBh, nrm, cand,
        XtBh, XtBl, XcBh, XcBl, WT1h, WT1l, b1, Xn_t, Xn_c);
    k_rescore<<<dim3(NT, BATCH), 64, 0, stream>>>(Q, P, cand, knn, counts);
  } else {
    // proven serial order: dist -> rescore -> gemms (outputs alias rescore inputs)
    k_main<<<dim3(1024), 256, 0, stream>>>(
        (const __bf16*)XcBh, (const __bf16*)XtBh, nrm, cand,
        XtBh, XtBl, XcBh, XcBl, WT1h, WT1l, b1, Xn_t, Xn_c);
    k_rescore<<<dim3(NT, BATCH), 64, 0, stream>>>(Q, P, cand, knn, counts);
    k_gemm_mfma<<<dim3(NT / 32, BATCH), 256, 0, stream>>>(XtBh, XtBl, WT1h, WT1l, b1, Xn_t, NT);
    k_gemm_mfma<<<dim3(NCTX / 32, BATCH), 256, 0, stream>>>(XcBh, XcBl, WT1h, WT1l, b1, Xn_c, NCTX);
  }

  // edge mean-pool -> Q as bf16 hi/lo
  k_gather<<<dim3(NT, BATCH), 256, 0, stream>>>(Xn_t, Xn_c, knn, XeH, XeL);

  // P dead now (XcT consumed by rescore; fallback Xn_c consumed by gather) -> contrib
  hipMemsetAsync(P, 0, (size_t)BATCH * NCTX * CH * 4, stream);

  // fused edge2node + out_t + X_et rows (in R)
  k_g2f<<<dim3(NT / 32, BATCH), 256, 0, stream>>>(XeH, XeL, WT2h, WT2l, b2, out_t, R);

  // context scatter-mean
  k_scatter<<<dim3(NT, BATCH), 256, 0, stream>>>(R, knn, P);
  k_fin_c<<<dim3(NCTX / 128, CH / 32, BATCH), tb, 0, stream>>>(P, counts, out_c1, out_c2);
}